// Round 7
// baseline (398.883 us; speedup 1.0000x reference)
//
#include <hip/hip_runtime.h>

#define DN 64
#define DE 32
#define DO 64
#define NB 256   // scan phase-1 blocks (requires n_nodes <= NB*256)
#define TP 256   // CSR positions per agg block

// ---------------------------------------------------------------------------
// K1: per-node projections through the edge-MLP weight:
//   Ps[n] = node[n] @ W_e[0:64], Pd[n] = node[n] @ W_e[96:160]
// ---------------------------------------------------------------------------
__global__ void __launch_bounds__(256) node_pre_kernel(
    const float* __restrict__ node, const float* __restrict__ W_e,
    float* __restrict__ Ps, float* __restrict__ Pd, int n_nodes)
{
    const int lane = threadIdx.x & 63;
    const int wid  = __builtin_amdgcn_readfirstlane((int)(threadIdx.x >> 6));
    const int wpb  = blockDim.x >> 6;
    const int gw   = blockIdx.x * wpb + wid;
    const int nw   = gridDim.x * wpb;

    float Ws[64], Wd[64];
#pragma unroll
    for (int k = 0; k < 64; ++k) {
        Ws[k] = W_e[k * DO + lane];
        Wd[k] = W_e[(96 + k) * DO + lane];
    }

    for (int n = gw; n < n_nodes; n += nw) {
        const float* __restrict__ x = node + (size_t)n * DN;
        float as = 0.f, ad = 0.f;
#pragma unroll
        for (int k = 0; k < 64; ++k) {
            const float xk = x[k];
            as = fmaf(xk, Ws[k], as);
            ad = fmaf(xk, Wd[k], ad);
        }
        Ps[(size_t)n * DO + lane] = as;
        Pd[(size_t)n * DO + lane] = ad;
    }
}

// ---------------------------------------------------------------------------
// K2: degree histogram
// ---------------------------------------------------------------------------
__global__ void __launch_bounds__(256) hist_kernel(
    const int* __restrict__ dst, int* __restrict__ cnt, int n_edges)
{
    int e = blockIdx.x * blockDim.x + threadIdx.x;
    if (e < n_edges) atomicAdd(&cnt[dst[e]], 1);
}

// ---------------------------------------------------------------------------
// K3a/b/c: parallel exclusive scan (3 phases)
// ---------------------------------------------------------------------------
__global__ void __launch_bounds__(256) scan_partial(
    const int* __restrict__ cnt, int* __restrict__ local,
    int* __restrict__ bsum, int n_nodes)
{
    const int C = (n_nodes + NB - 1) / NB;
    const int t = threadIdx.x, lane = t & 63, w = t >> 6;
    const int i = blockIdx.x * C + t;

    int v = (t < C && i < n_nodes) ? cnt[i] : 0;
    int incl = v;
#pragma unroll
    for (int off = 1; off < 64; off <<= 1) {
        int u = __shfl_up(incl, off, 64);
        if (lane >= off) incl += u;
    }
    __shared__ int ws[4], wo[4];
    if (lane == 63) ws[w] = incl;
    __syncthreads();
    if (t == 0) {
        int r = 0;
#pragma unroll
        for (int q = 0; q < 4; ++q) { wo[q] = r; r += ws[q]; }
        bsum[blockIdx.x] = r;
    }
    __syncthreads();
    if (t < C && i < n_nodes) local[i] = incl - v + wo[w];
}

__global__ void __launch_bounds__(NB) scan_bsum(
    int* __restrict__ bsum, int* __restrict__ row_start, int n_nodes)
{
    const int t = threadIdx.x, lane = t & 63, w = t >> 6;
    int v = bsum[t];
    int incl = v;
#pragma unroll
    for (int off = 1; off < 64; off <<= 1) {
        int u = __shfl_up(incl, off, 64);
        if (lane >= off) incl += u;
    }
    __shared__ int ws[4], wo[4];
    if (lane == 63) ws[w] = incl;
    __syncthreads();
    if (t == 0) {
        int r = 0;
#pragma unroll
        for (int q = 0; q < 4; ++q) { wo[q] = r; r += ws[q]; }
    }
    __syncthreads();
    int excl = incl - v + wo[w];
    bsum[t] = excl;
    if (t == NB - 1) row_start[n_nodes] = excl + v;
}

__global__ void __launch_bounds__(256) scan_add(
    const int* __restrict__ local, const int* __restrict__ bsum,
    int* __restrict__ row_start, int* __restrict__ cursor, int n_nodes)
{
    const int C = (n_nodes + NB - 1) / NB;
    const int i = blockIdx.x * C + threadIdx.x;
    if (threadIdx.x < C && i < n_nodes) {
        int r = local[i] + bsum[blockIdx.x];
        row_start[i] = r;
        cursor[i]    = r;
    }
}

// ---------------------------------------------------------------------------
// K4: scatter (edge_id, src_id, dst_id, 0) int4 records into CSR order.
// ---------------------------------------------------------------------------
__global__ void __launch_bounds__(256) scatter_kernel(
    const int* __restrict__ dst, const int* __restrict__ src,
    int* __restrict__ cursor, int4* __restrict__ csr, int n_edges)
{
    int e = blockIdx.x * blockDim.x + threadIdx.x;
    if (e < n_edges) {
        int d = dst[e];
        int p = atomicAdd(&cursor[d], 1);
        csr[p] = make_int4(e, src[e], d, 0);
    }
}

// ---------------------------------------------------------------------------
// K5: fused edge-message + segment aggregation, block per TP=256 CSR
// positions (NOT per node). Stage phase: all 256 threads cooperatively load
// exactly the 256 needed edge rows into LDS (8 threads x float4 per row).
// Compute phase: wave w walks its 64 contiguous positions; edge row comes
// from uniform-address ds_read (broadcast, conflict-free); one Ps gather
// per position (L2/L3-resident 12.8MB table); Pd reloaded only on segment
// change. Segment sums accumulate in a register; flush = plain store if the
// segment is interior to this wave's window, else unsafeAtomicAdd (only
// window-spanning segments, ~1 per 64-position boundary).
// ---------------------------------------------------------------------------
__global__ void __launch_bounds__(256) agg_tile_kernel(
    const float* __restrict__ edge,
    const float* __restrict__ W_e, const float* __restrict__ b_e,
    const float* __restrict__ Ps, const float* __restrict__ Pd,
    const int* __restrict__ row_start, const int4* __restrict__ csr,
    float* __restrict__ msum, int n_edges)
{
    __shared__ float lds_er[TP][32];   // 32 KB
    __shared__ int4  lds_pr[TP];       // 4 KB

    const int t    = threadIdx.x;
    const int lane = t & 63;
    const int wid  = __builtin_amdgcn_readfirstlane((int)(t >> 6));
    const int j0   = blockIdx.x * TP;

    // ---- stage phase ----
    {
        int j = j0 + t;
        lds_pr[t] = (j < n_edges) ? csr[j] : make_int4(0, 0, -1, 0);
    }
    {
        const int rr = t >> 3;            // 0..31: row within pass
        const int c4 = (t & 7) << 2;      // float col 0,4,...,28
#pragma unroll
        for (int p = 0; p < 8; ++p) {
            const int row = p * 32 + rr;
            const int j   = j0 + row;
            const int e   = (j < n_edges) ? csr[j].x : 0;  // 8-lane broadcast read
            const float4 v = *(const float4*)(edge + (size_t)e * DE + c4);
            *(float4*)(&lds_er[row][c4]) = v;
        }
    }

    // weights while staging is in flight
    float Wm[32];
#pragma unroll
    for (int k = 0; k < 32; ++k)
        Wm[k] = W_e[(64 + k) * DO + lane];
    const float bj = b_e[lane];

    __syncthreads();

    // ---- compute phase ----
    const int wbeg = j0 + wid * 64;
    int wcnt = n_edges - wbeg;
    if (wcnt > 64) wcnt = 64;

    float acc = 0.f, pdv = 0.f;
    int cur_d = -1;

    for (int p = 0; p < wcnt; ++p) {
        const int lp = wid * 64 + p;
        const int4 pr = lds_pr[lp];                              // uniform ds_read
        const int s = __builtin_amdgcn_readfirstlane(pr.y);
        const int d = __builtin_amdgcn_readfirstlane(pr.z);
        const float ps = Ps[(unsigned)s * DO + lane];            // issue early

        if (d != cur_d) {                                        // wave-uniform branch
            if (cur_d >= 0) {
                // segment ended inside this window; interior iff it started here
                if (row_start[cur_d] >= wbeg)
                    msum[(size_t)cur_d * DO + lane] = acc;
                else
                    unsafeAtomicAdd(&msum[(size_t)cur_d * DO + lane], acc);
            }
            acc = 0.f;
            cur_d = d;
            pdv = Pd[(unsigned)d * DO + lane];
        }

        const float* __restrict__ lrow = &lds_er[lp][0];
        float m0 = bj + pdv + ps, m1 = 0.f, m2 = 0.f, m3 = 0.f;
#pragma unroll
        for (int k = 0; k < 32; k += 4) {
            m0 = fmaf(lrow[k],     Wm[k],     m0);
            m1 = fmaf(lrow[k + 1], Wm[k + 1], m1);
            m2 = fmaf(lrow[k + 2], Wm[k + 2], m2);
            m3 = fmaf(lrow[k + 3], Wm[k + 3], m3);
        }
        acc += fmaxf((m0 + m1) + (m2 + m3), 0.f);
    }

    if (cur_d >= 0) {
        const int sb = row_start[cur_d];
        const int se = row_start[cur_d + 1];
        if (sb >= wbeg && se <= wbeg + wcnt)
            msum[(size_t)cur_d * DO + lane] = acc;
        else
            unsafeAtomicAdd(&msum[(size_t)cur_d * DO + lane], acc);
    }
}

// ---------------------------------------------------------------------------
// K6: node update: out = relu((msum/deg)@W_v[0:64] + node@W_v[64:128] + b_v)
// ---------------------------------------------------------------------------
__global__ void __launch_bounds__(256) node_out_kernel(
    const float* __restrict__ node, const float* __restrict__ msum,
    const int* __restrict__ row_start,
    const float* __restrict__ W_v, const float* __restrict__ b_v,
    float* __restrict__ out, int n_nodes)
{
    const int lane = threadIdx.x & 63;
    const int wid  = __builtin_amdgcn_readfirstlane((int)(threadIdx.x >> 6));
    const int wpb  = blockDim.x >> 6;
    const int gw   = blockIdx.x * wpb + wid;
    const int nw   = gridDim.x * wpb;

    float Wt[64], Wb[64];
#pragma unroll
    for (int k = 0; k < 64; ++k) {
        Wt[k] = W_v[k * DO + lane];
        Wb[k] = W_v[(64 + k) * DO + lane];
    }
    const float bj = b_v[lane];

    for (int n = gw; n < n_nodes; n += nw) {
        const float* __restrict__ ms = msum + (size_t)n * DO;
        const float* __restrict__ x  = node + (size_t)n * DN;
        const float dg = (float)(row_start[n + 1] - row_start[n]);
        float an = 0.f, ax = 0.f;
#pragma unroll
        for (int k = 0; k < 64; ++k) {
            an = fmaf(ms[k], Wt[k], an);
            ax = fmaf(x[k],  Wb[k], ax);
        }
        float acc = bj + ax + (dg > 0.f ? an / dg : 0.f);
        out[(size_t)n * DO + lane] = fmaxf(acc, 0.f);
    }
}

extern "C" void kernel_launch(void* const* d_in, const int* in_sizes, int n_in,
                              void* d_out, int out_size, void* d_ws, size_t ws_size,
                              hipStream_t stream)
{
    const float* node = (const float*)d_in[0];
    const float* edge = (const float*)d_in[1];
    const int*   src  = (const int*)d_in[2];
    const int*   dst  = (const int*)d_in[3];
    const float* W_e  = (const float*)d_in[4];
    const float* b_e  = (const float*)d_in[5];
    const float* W_v  = (const float*)d_in[6];
    const float* b_v  = (const float*)d_in[7];
    float* out = (float*)d_out;

    const int n_nodes = in_sizes[0] / DN;
    const int n_edges = in_sizes[2];

    // Workspace: Ps | Pd | msum (floats) | row_start | cnt | cursor | local | bsum | csr(int4)
    float* Ps   = (float*)d_ws;
    float* Pd   = Ps   + (size_t)n_nodes * DO;
    float* msum = Pd   + (size_t)n_nodes * DO;
    int* row_start = (int*)(msum + (size_t)n_nodes * DO);
    int* cnt       = row_start + (n_nodes + 1);
    int* cursor    = cnt + n_nodes;
    int* local     = cursor + n_nodes;
    int* bsum      = local + n_nodes;
    int4* csr      = (int4*)(((size_t)(bsum + NB) + 15) & ~(size_t)15);

    // zero msum (atomic base for window-spanning segments) + cnt
    hipMemsetAsync(msum, 0, (size_t)n_nodes * DO * sizeof(float), stream);
    hipMemsetAsync(cnt, 0, (size_t)n_nodes * sizeof(int), stream);

    node_pre_kernel<<<512, 256, 0, stream>>>(node, W_e, Ps, Pd, n_nodes);
    hist_kernel<<<(n_edges + 255) / 256, 256, 0, stream>>>(dst, cnt, n_edges);
    scan_partial<<<NB, 256, 0, stream>>>(cnt, local, bsum, n_nodes);
    scan_bsum<<<1, NB, 0, stream>>>(bsum, row_start, n_nodes);
    scan_add<<<NB, 256, 0, stream>>>(local, bsum, row_start, cursor, n_nodes);
    scatter_kernel<<<(n_edges + 255) / 256, 256, 0, stream>>>(dst, src, cursor, csr, n_edges);
    agg_tile_kernel<<<(n_edges + TP - 1) / TP, 256, 0, stream>>>(edge, W_e, b_e, Ps, Pd,
                                                                 row_start, csr, msum, n_edges);
    node_out_kernel<<<512, 256, 0, stream>>>(node, msum, row_start, W_v, b_v,
                                             out, n_nodes);
}

// Round 8
// 342.830 us; speedup vs baseline: 1.1635x; 1.1635x over previous
//
#include <hip/hip_runtime.h>

#define DN 64
#define DE 32
#define DO 64
#define NB 256   // scan phase-1 blocks (requires n_nodes <= NB*256)
#define TP 256   // CSR positions per agg block
#define CH 8     // Ps prefetch chunk (double-buffered)

// ---------------------------------------------------------------------------
// K1: fused per-node projections + degree histogram.
// Section A (nodes): Ps[n] = node[n]@W_e[0:64], Pd[n] = node[n]@W_e[96:160]
// Section B (edges): cnt[dst[e]]++
// ---------------------------------------------------------------------------
__global__ void __launch_bounds__(256) pre_hist_kernel(
    const float* __restrict__ node, const float* __restrict__ W_e,
    const int* __restrict__ dst,
    float* __restrict__ Ps, float* __restrict__ Pd,
    int* __restrict__ cnt, int n_nodes, int n_edges)
{
    const int lane = threadIdx.x & 63;
    const int wid  = __builtin_amdgcn_readfirstlane((int)(threadIdx.x >> 6));
    const int wpb  = blockDim.x >> 6;
    const int gw   = blockIdx.x * wpb + wid;
    const int nw   = gridDim.x * wpb;

    float Ws[64], Wd[64];
#pragma unroll
    for (int k = 0; k < 64; ++k) {
        Ws[k] = W_e[k * DO + lane];
        Wd[k] = W_e[(96 + k) * DO + lane];
    }

    for (int n = gw; n < n_nodes; n += nw) {
        const float* __restrict__ x = node + (size_t)n * DN;
        float as = 0.f, ad = 0.f;
#pragma unroll
        for (int k = 0; k < 64; ++k) {
            const float xk = x[k];
            as = fmaf(xk, Ws[k], as);
            ad = fmaf(xk, Wd[k], ad);
        }
        Ps[(size_t)n * DO + lane] = as;
        Pd[(size_t)n * DO + lane] = ad;
    }

    const int gt = blockIdx.x * blockDim.x + threadIdx.x;
    const int nt = gridDim.x * blockDim.x;
    for (int e = gt; e < n_edges; e += nt)
        atomicAdd(&cnt[dst[e]], 1);
}

// ---------------------------------------------------------------------------
// K3a/b/c: parallel exclusive scan (3 phases)
// ---------------------------------------------------------------------------
__global__ void __launch_bounds__(256) scan_partial(
    const int* __restrict__ cnt, int* __restrict__ local,
    int* __restrict__ bsum, int n_nodes)
{
    const int C = (n_nodes + NB - 1) / NB;
    const int t = threadIdx.x, lane = t & 63, w = t >> 6;
    const int i = blockIdx.x * C + t;

    int v = (t < C && i < n_nodes) ? cnt[i] : 0;
    int incl = v;
#pragma unroll
    for (int off = 1; off < 64; off <<= 1) {
        int u = __shfl_up(incl, off, 64);
        if (lane >= off) incl += u;
    }
    __shared__ int ws[4], wo[4];
    if (lane == 63) ws[w] = incl;
    __syncthreads();
    if (t == 0) {
        int r = 0;
#pragma unroll
        for (int q = 0; q < 4; ++q) { wo[q] = r; r += ws[q]; }
        bsum[blockIdx.x] = r;
    }
    __syncthreads();
    if (t < C && i < n_nodes) local[i] = incl - v + wo[w];
}

__global__ void __launch_bounds__(NB) scan_bsum(
    int* __restrict__ bsum, int* __restrict__ row_start, int n_nodes)
{
    const int t = threadIdx.x, lane = t & 63, w = t >> 6;
    int v = bsum[t];
    int incl = v;
#pragma unroll
    for (int off = 1; off < 64; off <<= 1) {
        int u = __shfl_up(incl, off, 64);
        if (lane >= off) incl += u;
    }
    __shared__ int ws[4], wo[4];
    if (lane == 63) ws[w] = incl;
    __syncthreads();
    if (t == 0) {
        int r = 0;
#pragma unroll
        for (int q = 0; q < 4; ++q) { wo[q] = r; r += ws[q]; }
    }
    __syncthreads();
    int excl = incl - v + wo[w];
    bsum[t] = excl;
    if (t == NB - 1) row_start[n_nodes] = excl + v;
}

__global__ void __launch_bounds__(256) scan_add(
    const int* __restrict__ local, const int* __restrict__ bsum,
    int* __restrict__ row_start, int* __restrict__ cursor, int n_nodes)
{
    const int C = (n_nodes + NB - 1) / NB;
    const int i = blockIdx.x * C + threadIdx.x;
    if (threadIdx.x < C && i < n_nodes) {
        int r = local[i] + bsum[blockIdx.x];
        row_start[i] = r;
        cursor[i]    = r;
    }
}

// ---------------------------------------------------------------------------
// K4: scatter (edge_id, src_id, dst_id, 0) int4 records into CSR order.
// ---------------------------------------------------------------------------
__global__ void __launch_bounds__(256) scatter_kernel(
    const int* __restrict__ dst, const int* __restrict__ src,
    int* __restrict__ cursor, int4* __restrict__ csr, int n_edges)
{
    int e = blockIdx.x * blockDim.x + threadIdx.x;
    if (e < n_edges) {
        int d = dst[e];
        int p = atomicAdd(&cursor[d], 1);
        csr[p] = make_int4(e, src[e], d, 0);
    }
}

// ---------------------------------------------------------------------------
// K5: fused edge-message + segment aggregation, block per TP=256 CSR
// positions. Stage: 256 edge rows -> LDS (coalesced, 8 threads/row).
// Compute: wave walks 64 contiguous positions; per-position Ps gather is
// DOUBLE-BUFFER CHUNK-PREFETCHED (CH=8): while FMA-ing chunk c (~800 cyc),
// chunk c+1's 8 gathers (L3-resident table, ~500 cyc) are in flight.
// All pc[]/pn[] indices static via full unroll (no scratch). Segment sums
// in registers; interior segments plain-store, window-spanning ones
// unsafeAtomicAdd (~1 per wave boundary).
// ---------------------------------------------------------------------------
__global__ void __launch_bounds__(256) agg_tile_kernel(
    const float* __restrict__ edge,
    const float* __restrict__ W_e, const float* __restrict__ b_e,
    const float* __restrict__ Ps, const float* __restrict__ Pd,
    const int* __restrict__ row_start, const int4* __restrict__ csr,
    float* __restrict__ msum, int n_edges)
{
    __shared__ float lds_er[TP][32];   // 32 KB

    const int t    = threadIdx.x;
    const int lane = t & 63;
    const int wid  = __builtin_amdgcn_readfirstlane((int)(t >> 6));
    const int j0   = blockIdx.x * TP;

    // ---- stage phase: 256 edge rows, 8 threads x float4 each ----
    {
        const int rr = t >> 3;            // 0..31
        const int c4 = (t & 7) << 2;      // float col 0,4,...,28
#pragma unroll
        for (int p = 0; p < 8; ++p) {
            const int row = p * 32 + rr;
            const int j   = j0 + row;
            const int e   = (j < n_edges) ? csr[j].x : 0;
            const float4 v = *(const float4*)(edge + (size_t)e * DE + c4);
            *(float4*)(&lds_er[row][c4]) = v;
        }
    }

    float Wm[32];
#pragma unroll
    for (int k = 0; k < 32; ++k)
        Wm[k] = W_e[(64 + k) * DO + lane];
    const float bj = b_e[lane];

    const int wbeg = j0 + wid * 64;
    int wcnt = n_edges - wbeg;
    if (wcnt > 64) wcnt = 64;

    int4 my4 = make_int4(0, 0, -1, 0);
    if (wcnt > 0) my4 = csr[min(wbeg + lane, n_edges - 1)];

    __syncthreads();
    if (wcnt <= 0) return;   // only trailing waves of the last block

    float acc = 0.f, bpd = 0.f;
    int cur_d = -1;

    // prologue: prefetch chunk 0
    float pn[CH];
#pragma unroll
    for (int q = 0; q < CH; ++q) {
        const int s = __builtin_amdgcn_readlane(my4.y, min(q, wcnt - 1));
        pn[q] = Ps[(unsigned)s * DO + lane];
    }

    for (int c = 0; c < wcnt; c += CH) {
        float pc[CH];
#pragma unroll
        for (int q = 0; q < CH; ++q) pc[q] = pn[q];
        // issue next chunk's gathers (clamped; wasted only at the tail)
#pragma unroll
        for (int q = 0; q < CH; ++q) {
            const int s = __builtin_amdgcn_readlane(my4.y, min(c + CH + q, wcnt - 1));
            pn[q] = Ps[(unsigned)s * DO + lane];
        }
#pragma unroll
        for (int q = 0; q < CH; ++q) {
            const int p = c + q;
            if (p < wcnt) {                                  // wave-uniform
                const int d = __builtin_amdgcn_readlane(my4.z, p);
                if (d != cur_d) {                            // wave-uniform
                    if (cur_d >= 0) {
                        if (row_start[cur_d] >= wbeg)
                            msum[(size_t)cur_d * DO + lane] = acc;
                        else
                            unsafeAtomicAdd(&msum[(size_t)cur_d * DO + lane], acc);
                    }
                    acc = 0.f;
                    cur_d = d;
                    bpd = bj + Pd[(unsigned)d * DO + lane];
                }
                const float* __restrict__ lrow = &lds_er[wid * 64 + p][0];
                float m0 = bpd + pc[q], m1 = 0.f, m2 = 0.f, m3 = 0.f;
#pragma unroll
                for (int k = 0; k < 32; k += 4) {
                    m0 = fmaf(lrow[k],     Wm[k],     m0);
                    m1 = fmaf(lrow[k + 1], Wm[k + 1], m1);
                    m2 = fmaf(lrow[k + 2], Wm[k + 2], m2);
                    m3 = fmaf(lrow[k + 3], Wm[k + 3], m3);
                }
                acc += fmaxf((m0 + m1) + (m2 + m3), 0.f);
            }
        }
    }

    {   // final flush
        const int sb = row_start[cur_d];
        const int se = row_start[cur_d + 1];
        if (sb >= wbeg && se <= wbeg + wcnt)
            msum[(size_t)cur_d * DO + lane] = acc;
        else
            unsafeAtomicAdd(&msum[(size_t)cur_d * DO + lane], acc);
    }
}

// ---------------------------------------------------------------------------
// K6: node update: out = relu((msum/deg)@W_v[0:64] + node@W_v[64:128] + b_v)
// ---------------------------------------------------------------------------
__global__ void __launch_bounds__(256) node_out_kernel(
    const float* __restrict__ node, const float* __restrict__ msum,
    const int* __restrict__ row_start,
    const float* __restrict__ W_v, const float* __restrict__ b_v,
    float* __restrict__ out, int n_nodes)
{
    const int lane = threadIdx.x & 63;
    const int wid  = __builtin_amdgcn_readfirstlane((int)(threadIdx.x >> 6));
    const int wpb  = blockDim.x >> 6;
    const int gw   = blockIdx.x * wpb + wid;
    const int nw   = gridDim.x * wpb;

    float Wt[64], Wb[64];
#pragma unroll
    for (int k = 0; k < 64; ++k) {
        Wt[k] = W_v[k * DO + lane];
        Wb[k] = W_v[(64 + k) * DO + lane];
    }
    const float bj = b_v[lane];

    for (int n = gw; n < n_nodes; n += nw) {
        const float* __restrict__ ms = msum + (size_t)n * DO;
        const float* __restrict__ x  = node + (size_t)n * DN;
        const float dg = (float)(row_start[n + 1] - row_start[n]);
        float an = 0.f, ax = 0.f;
#pragma unroll
        for (int k = 0; k < 64; ++k) {
            an = fmaf(ms[k], Wt[k], an);
            ax = fmaf(x[k],  Wb[k], ax);
        }
        float acc = bj + ax + (dg > 0.f ? an / dg : 0.f);
        out[(size_t)n * DO + lane] = fmaxf(acc, 0.f);
    }
}

extern "C" void kernel_launch(void* const* d_in, const int* in_sizes, int n_in,
                              void* d_out, int out_size, void* d_ws, size_t ws_size,
                              hipStream_t stream)
{
    const float* node = (const float*)d_in[0];
    const float* edge = (const float*)d_in[1];
    const int*   src  = (const int*)d_in[2];
    const int*   dst  = (const int*)d_in[3];
    const float* W_e  = (const float*)d_in[4];
    const float* b_e  = (const float*)d_in[5];
    const float* W_v  = (const float*)d_in[6];
    const float* b_v  = (const float*)d_in[7];
    float* out = (float*)d_out;

    const int n_nodes = in_sizes[0] / DN;
    const int n_edges = in_sizes[2];

    // Workspace: Ps | Pd | msum (floats) | row_start | cnt | cursor | local | bsum | csr(int4)
    float* Ps   = (float*)d_ws;
    float* Pd   = Ps   + (size_t)n_nodes * DO;
    float* msum = Pd   + (size_t)n_nodes * DO;
    int* row_start = (int*)(msum + (size_t)n_nodes * DO);
    int* cnt       = row_start + (n_nodes + 1);
    int* cursor    = cnt + n_nodes;
    int* local     = cursor + n_nodes;
    int* bsum      = local + n_nodes;
    int4* csr      = (int4*)(((size_t)(bsum + NB) + 15) & ~(size_t)15);

    hipMemsetAsync(msum, 0, (size_t)n_nodes * DO * sizeof(float), stream);
    hipMemsetAsync(cnt, 0, (size_t)n_nodes * sizeof(int), stream);

    pre_hist_kernel<<<512, 256, 0, stream>>>(node, W_e, dst, Ps, Pd, cnt,
                                             n_nodes, n_edges);
    scan_partial<<<NB, 256, 0, stream>>>(cnt, local, bsum, n_nodes);
    scan_bsum<<<1, NB, 0, stream>>>(bsum, row_start, n_nodes);
    scan_add<<<NB, 256, 0, stream>>>(local, bsum, row_start, cursor, n_nodes);
    scatter_kernel<<<(n_edges + 255) / 256, 256, 0, stream>>>(dst, src, cursor, csr, n_edges);
    agg_tile_kernel<<<(n_edges + TP - 1) / TP, 256, 0, stream>>>(edge, W_e, b_e, Ps, Pd,
                                                                 row_start, csr, msum, n_edges);
    node_out_kernel<<<512, 256, 0, stream>>>(node, msum, row_start, W_v, b_v,
                                             out, n_nodes);
}

// Round 9
// 333.737 us; speedup vs baseline: 1.1952x; 1.0272x over previous
//
#include <hip/hip_runtime.h>

#define DN 64
#define DE 32
#define DO 64
#define NB 256   // scan phase-1 blocks (requires n_nodes <= NB*256)
#define TP 128   // CSR positions per agg block (2 waves x 64)
#define CH 8     // Ps prefetch chunk (double-buffered)

// ---------------------------------------------------------------------------
// K1: fused per-node projections + degree histogram.
// ---------------------------------------------------------------------------
__global__ void __launch_bounds__(256) pre_hist_kernel(
    const float* __restrict__ node, const float* __restrict__ W_e,
    const int* __restrict__ dst,
    float* __restrict__ Ps, float* __restrict__ Pd,
    int* __restrict__ cnt, int n_nodes, int n_edges)
{
    const int lane = threadIdx.x & 63;
    const int wid  = __builtin_amdgcn_readfirstlane((int)(threadIdx.x >> 6));
    const int wpb  = blockDim.x >> 6;
    const int gw   = blockIdx.x * wpb + wid;
    const int nw   = gridDim.x * wpb;

    float Ws[64], Wd[64];
#pragma unroll
    for (int k = 0; k < 64; ++k) {
        Ws[k] = W_e[k * DO + lane];
        Wd[k] = W_e[(96 + k) * DO + lane];
    }

    for (int n = gw; n < n_nodes; n += nw) {
        const float* __restrict__ x = node + (size_t)n * DN;
        float as = 0.f, ad = 0.f;
#pragma unroll
        for (int k = 0; k < 64; ++k) {
            const float xk = x[k];
            as = fmaf(xk, Ws[k], as);
            ad = fmaf(xk, Wd[k], ad);
        }
        Ps[(size_t)n * DO + lane] = as;
        Pd[(size_t)n * DO + lane] = ad;
    }

    const int gt = blockIdx.x * blockDim.x + threadIdx.x;
    const int nt = gridDim.x * blockDim.x;
    for (int e = gt; e < n_edges; e += nt)
        atomicAdd(&cnt[dst[e]], 1);
}

// ---------------------------------------------------------------------------
// K3a/b/c: parallel exclusive scan (3 phases)
// ---------------------------------------------------------------------------
__global__ void __launch_bounds__(256) scan_partial(
    const int* __restrict__ cnt, int* __restrict__ local,
    int* __restrict__ bsum, int n_nodes)
{
    const int C = (n_nodes + NB - 1) / NB;
    const int t = threadIdx.x, lane = t & 63, w = t >> 6;
    const int i = blockIdx.x * C + t;

    int v = (t < C && i < n_nodes) ? cnt[i] : 0;
    int incl = v;
#pragma unroll
    for (int off = 1; off < 64; off <<= 1) {
        int u = __shfl_up(incl, off, 64);
        if (lane >= off) incl += u;
    }
    __shared__ int ws[4], wo[4];
    if (lane == 63) ws[w] = incl;
    __syncthreads();
    if (t == 0) {
        int r = 0;
#pragma unroll
        for (int q = 0; q < 4; ++q) { wo[q] = r; r += ws[q]; }
        bsum[blockIdx.x] = r;
    }
    __syncthreads();
    if (t < C && i < n_nodes) local[i] = incl - v + wo[w];
}

__global__ void __launch_bounds__(NB) scan_bsum(
    int* __restrict__ bsum, int* __restrict__ row_start, int n_nodes)
{
    const int t = threadIdx.x, lane = t & 63, w = t >> 6;
    int v = bsum[t];
    int incl = v;
#pragma unroll
    for (int off = 1; off < 64; off <<= 1) {
        int u = __shfl_up(incl, off, 64);
        if (lane >= off) incl += u;
    }
    __shared__ int ws[4], wo[4];
    if (lane == 63) ws[w] = incl;
    __syncthreads();
    if (t == 0) {
        int r = 0;
#pragma unroll
        for (int q = 0; q < 4; ++q) { wo[q] = r; r += ws[q]; }
    }
    __syncthreads();
    int excl = incl - v + wo[w];
    bsum[t] = excl;
    if (t == NB - 1) row_start[n_nodes] = excl + v;
}

__global__ void __launch_bounds__(256) scan_add(
    const int* __restrict__ local, const int* __restrict__ bsum,
    int* __restrict__ row_start, int* __restrict__ cursor, int n_nodes)
{
    const int C = (n_nodes + NB - 1) / NB;
    const int i = blockIdx.x * C + threadIdx.x;
    if (threadIdx.x < C && i < n_nodes) {
        int r = local[i] + bsum[blockIdx.x];
        row_start[i] = r;
        cursor[i]    = r;
    }
}

// ---------------------------------------------------------------------------
// K4: scatter (edge_id, src_id, dst_id, 0) int4 records into CSR order.
// ---------------------------------------------------------------------------
__global__ void __launch_bounds__(256) scatter_kernel(
    const int* __restrict__ dst, const int* __restrict__ src,
    int* __restrict__ cursor, int4* __restrict__ csr, int n_edges)
{
    int e = blockIdx.x * blockDim.x + threadIdx.x;
    if (e < n_edges) {
        int d = dst[e];
        int p = atomicAdd(&cursor[d], 1);
        csr[p] = make_int4(e, src[e], d, 0);
    }
}

// ---------------------------------------------------------------------------
// K5: fused edge-message + segment aggregation.
// TP=128 positions per 128-thread (2-wave) block -> 16KB LDS -> ~10 blocks/CU
// (vs 3 at 32KB): double the latency-hiding TLP. Fast path (window full, the
// only case when TP | n_edges) has no clamps / bounds checks per position.
// ---------------------------------------------------------------------------
__global__ void __launch_bounds__(128) agg_tile_kernel(
    const float* __restrict__ edge,
    const float* __restrict__ W_e, const float* __restrict__ b_e,
    const float* __restrict__ Ps, const float* __restrict__ Pd,
    const int* __restrict__ row_start, const int4* __restrict__ csr,
    float* __restrict__ msum, int n_edges)
{
    __shared__ float lds_er[TP][32];   // 16 KB

    const int t    = threadIdx.x;
    const int lane = t & 63;
    const int wid  = __builtin_amdgcn_readfirstlane((int)(t >> 6));
    const int j0   = blockIdx.x * TP;

    // ---- stage phase: 128 edge rows, 8 threads x float4 each, 8 passes ----
    {
        const int rr = t >> 3;            // 0..15
        const int c4 = (t & 7) << 2;      // float col 0,4,...,28
#pragma unroll
        for (int p = 0; p < 8; ++p) {
            const int row = p * 16 + rr;
            const int j   = j0 + row;
            const int e   = (j < n_edges) ? csr[j].x : 0;
            const float4 v = *(const float4*)(edge + (size_t)e * DE + c4);
            *(float4*)(&lds_er[row][c4]) = v;
        }
    }

    float Wm[32];
#pragma unroll
    for (int k = 0; k < 32; ++k)
        Wm[k] = W_e[(64 + k) * DO + lane];
    const float bj = b_e[lane];

    const int wbeg = j0 + wid * 64;
    const int wcnt = min(n_edges - wbeg, 64);

    int4 my4 = make_int4(0, 0, -1, 0);
    if (wcnt > 0) my4 = csr[min(wbeg + lane, n_edges - 1)];

    __syncthreads();
    if (wcnt <= 0) return;

    float acc = 0.f, bpd = 0.f;
    int cur_d = -1;

    if (wcnt == 64) {
        // ================= fast path: full window, no clamps ==============
        float pn[CH];
#pragma unroll
        for (int q = 0; q < CH; ++q) {
            const int s = __builtin_amdgcn_readlane(my4.y, q);
            pn[q] = Ps[(unsigned)s * DO + lane];
        }
#pragma unroll
        for (int c = 0; c < 64; c += CH) {
            float pc[CH];
#pragma unroll
            for (int q = 0; q < CH; ++q) pc[q] = pn[q];
            if (c + CH < 64) {
#pragma unroll
                for (int q = 0; q < CH; ++q) {
                    const int s = __builtin_amdgcn_readlane(my4.y, c + CH + q);
                    pn[q] = Ps[(unsigned)s * DO + lane];
                }
            }
#pragma unroll
            for (int q = 0; q < CH; ++q) {
                const int p = c + q;
                const int d = __builtin_amdgcn_readlane(my4.z, p);
                if (d != cur_d) {
                    if (cur_d >= 0) {
                        if (row_start[cur_d] >= wbeg)
                            msum[(size_t)cur_d * DO + lane] = acc;
                        else
                            unsafeAtomicAdd(&msum[(size_t)cur_d * DO + lane], acc);
                    }
                    acc = 0.f;
                    cur_d = d;
                    bpd = bj + Pd[(unsigned)d * DO + lane];
                }
                const float* __restrict__ lrow = &lds_er[wid * 64 + p][0];
                float m0 = bpd + pc[q], m1 = 0.f, m2 = 0.f, m3 = 0.f;
#pragma unroll
                for (int k = 0; k < 32; k += 4) {
                    m0 = fmaf(lrow[k],     Wm[k],     m0);
                    m1 = fmaf(lrow[k + 1], Wm[k + 1], m1);
                    m2 = fmaf(lrow[k + 2], Wm[k + 2], m2);
                    m3 = fmaf(lrow[k + 3], Wm[k + 3], m3);
                }
                acc += fmaxf((m0 + m1) + (m2 + m3), 0.f);
            }
        }
    } else {
        // ================= generic tail path (clamped) ====================
        float pn[CH];
#pragma unroll
        for (int q = 0; q < CH; ++q) {
            const int s = __builtin_amdgcn_readlane(my4.y, min(q, wcnt - 1));
            pn[q] = Ps[(unsigned)s * DO + lane];
        }
        for (int c = 0; c < wcnt; c += CH) {
            float pc[CH];
#pragma unroll
            for (int q = 0; q < CH; ++q) pc[q] = pn[q];
#pragma unroll
            for (int q = 0; q < CH; ++q) {
                const int s = __builtin_amdgcn_readlane(my4.y, min(c + CH + q, wcnt - 1));
                pn[q] = Ps[(unsigned)s * DO + lane];
            }
#pragma unroll
            for (int q = 0; q < CH; ++q) {
                const int p = c + q;
                if (p < wcnt) {
                    const int d = __builtin_amdgcn_readlane(my4.z, p);
                    if (d != cur_d) {
                        if (cur_d >= 0) {
                            if (row_start[cur_d] >= wbeg)
                                msum[(size_t)cur_d * DO + lane] = acc;
                            else
                                unsafeAtomicAdd(&msum[(size_t)cur_d * DO + lane], acc);
                        }
                        acc = 0.f;
                        cur_d = d;
                        bpd = bj + Pd[(unsigned)d * DO + lane];
                    }
                    const float* __restrict__ lrow = &lds_er[wid * 64 + p][0];
                    float m0 = bpd + pc[q], m1 = 0.f, m2 = 0.f, m3 = 0.f;
#pragma unroll
                    for (int k = 0; k < 32; k += 4) {
                        m0 = fmaf(lrow[k],     Wm[k],     m0);
                        m1 = fmaf(lrow[k + 1], Wm[k + 1], m1);
                        m2 = fmaf(lrow[k + 2], Wm[k + 2], m2);
                        m3 = fmaf(lrow[k + 3], Wm[k + 3], m3);
                    }
                    acc += fmaxf((m0 + m1) + (m2 + m3), 0.f);
                }
            }
        }
    }

    {   // final flush
        const int sb = row_start[cur_d];
        const int se = row_start[cur_d + 1];
        if (sb >= wbeg && se <= wbeg + wcnt)
            msum[(size_t)cur_d * DO + lane] = acc;
        else
            unsafeAtomicAdd(&msum[(size_t)cur_d * DO + lane], acc);
    }
}

// ---------------------------------------------------------------------------
// K6: node update: out = relu((msum/deg)@W_v[0:64] + node@W_v[64:128] + b_v)
// ---------------------------------------------------------------------------
__global__ void __launch_bounds__(256) node_out_kernel(
    const float* __restrict__ node, const float* __restrict__ msum,
    const int* __restrict__ row_start,
    const float* __restrict__ W_v, const float* __restrict__ b_v,
    float* __restrict__ out, int n_nodes)
{
    const int lane = threadIdx.x & 63;
    const int wid  = __builtin_amdgcn_readfirstlane((int)(threadIdx.x >> 6));
    const int wpb  = blockDim.x >> 6;
    const int gw   = blockIdx.x * wpb + wid;
    const int nw   = gridDim.x * wpb;

    float Wt[64], Wb[64];
#pragma unroll
    for (int k = 0; k < 64; ++k) {
        Wt[k] = W_v[k * DO + lane];
        Wb[k] = W_v[(64 + k) * DO + lane];
    }
    const float bj = b_v[lane];

    for (int n = gw; n < n_nodes; n += nw) {
        const float* __restrict__ ms = msum + (size_t)n * DO;
        const float* __restrict__ x  = node + (size_t)n * DN;
        const float dg = (float)(row_start[n + 1] - row_start[n]);
        float an = 0.f, ax = 0.f;
#pragma unroll
        for (int k = 0; k < 64; ++k) {
            an = fmaf(ms[k], Wt[k], an);
            ax = fmaf(x[k],  Wb[k], ax);
        }
        float acc = bj + ax + (dg > 0.f ? an / dg : 0.f);
        out[(size_t)n * DO + lane] = fmaxf(acc, 0.f);
    }
}

extern "C" void kernel_launch(void* const* d_in, const int* in_sizes, int n_in,
                              void* d_out, int out_size, void* d_ws, size_t ws_size,
                              hipStream_t stream)
{
    const float* node = (const float*)d_in[0];
    const float* edge = (const float*)d_in[1];
    const int*   src  = (const int*)d_in[2];
    const int*   dst  = (const int*)d_in[3];
    const float* W_e  = (const float*)d_in[4];
    const float* b_e  = (const float*)d_in[5];
    const float* W_v  = (const float*)d_in[6];
    const float* b_v  = (const float*)d_in[7];
    float* out = (float*)d_out;

    const int n_nodes = in_sizes[0] / DN;
    const int n_edges = in_sizes[2];

    // Workspace: Ps | Pd | msum (floats) | row_start | cnt | cursor | local | bsum | csr(int4)
    float* Ps   = (float*)d_ws;
    float* Pd   = Ps   + (size_t)n_nodes * DO;
    float* msum = Pd   + (size_t)n_nodes * DO;
    int* row_start = (int*)(msum + (size_t)n_nodes * DO);
    int* cnt       = row_start + (n_nodes + 1);
    int* cursor    = cnt + n_nodes;
    int* local     = cursor + n_nodes;
    int* bsum      = local + n_nodes;
    int4* csr      = (int4*)(((size_t)(bsum + NB) + 15) & ~(size_t)15);

    hipMemsetAsync(msum, 0, (size_t)n_nodes * DO * sizeof(float), stream);
    hipMemsetAsync(cnt, 0, (size_t)n_nodes * sizeof(int), stream);

    pre_hist_kernel<<<512, 256, 0, stream>>>(node, W_e, dst, Ps, Pd, cnt,
                                             n_nodes, n_edges);
    scan_partial<<<NB, 256, 0, stream>>>(cnt, local, bsum, n_nodes);
    scan_bsum<<<1, NB, 0, stream>>>(bsum, row_start, n_nodes);
    scan_add<<<NB, 256, 0, stream>>>(local, bsum, row_start, cursor, n_nodes);
    scatter_kernel<<<(n_edges + 255) / 256, 256, 0, stream>>>(dst, src, cursor, csr, n_edges);
    agg_tile_kernel<<<(n_edges + TP - 1) / TP, 128, 0, stream>>>(edge, W_e, b_e, Ps, Pd,
                                                                 row_start, csr, msum, n_edges);
    node_out_kernel<<<512, 256, 0, stream>>>(node, msum, row_start, W_v, b_v,
                                             out, n_nodes);
}

// Round 10
// 262.406 us; speedup vs baseline: 1.5201x; 1.2718x over previous
//
#include <hip/hip_runtime.h>

#define DN 64
#define DE 32
#define DO 64
#define NB 256   // scan phase-1 blocks (requires n_nodes <= NB*256)
#define TP 128   // CSR positions per agg block (2 waves x 64)
#define CH 8     // Ps prefetch chunk (double-buffered)

__device__ inline unsigned pack_bf16(float a, float b) {
    unsigned ua = __float_as_uint(a), ub = __float_as_uint(b);
    ua = (ua + 0x7fffu + ((ua >> 16) & 1u)) >> 16;     // RNE bf16
    ub = (ub + 0x7fffu + ((ub >> 16) & 1u)) >> 16;
    return ua | (ub << 16);
}

// ---------------------------------------------------------------------------
// K1: tiled per-node projections + degree histogram.
// Tile of 64 node rows staged coalesced into LDS; rows then read via
// broadcast ds_read (no scalar-load chains). Waves 0,1 -> Ps (nodes 0-31 /
// 32-63 of the tile), waves 2,3 -> Pd. One tile per block.
// ---------------------------------------------------------------------------
__global__ void __launch_bounds__(256) pre_hist_kernel(
    const float* __restrict__ node, const float* __restrict__ W_e,
    const int* __restrict__ dst,
    float* __restrict__ Ps, float* __restrict__ Pd,
    int* __restrict__ cnt, int n_nodes, int n_edges)
{
    __shared__ float lds_x[64][64];   // 16 KB

    const int t    = threadIdx.x;
    const int lane = t & 63;
    const int w    = __builtin_amdgcn_readfirstlane((int)(t >> 6));
    const int nbase = blockIdx.x * 64;

    // stage 64 rows (4096 floats) coalesced: 4 float4 per thread
#pragma unroll
    for (int q = 0; q < 4; ++q) {
        const int f4 = q * 256 + t;          // 0..1023
        const int nn = f4 >> 4;              // 16 float4 per row
        const int cc = (f4 & 15) << 2;
        const int gn = nbase + nn;
        float4 v = make_float4(0.f, 0.f, 0.f, 0.f);
        if (gn < n_nodes) v = *(const float4*)(node + (size_t)gn * DN + cc);
        *(float4*)(&lds_x[nn][cc]) = v;
    }

    float Wc[64];
    const int wrow0 = (w < 2) ? 0 : 96;      // Ws rows 0..63 | Wd rows 96..159
#pragma unroll
    for (int k = 0; k < 64; ++k)
        Wc[k] = W_e[(wrow0 + k) * DO + lane];
    float* __restrict__ outbuf = (w < 2) ? Ps : Pd;
    const int nodes0 = (w & 1) * 32;

    __syncthreads();

    for (int i = 0; i < 32; ++i) {
        const int nn = nodes0 + i;
        const int gn = nbase + nn;
        if (gn >= n_nodes) break;            // wave-uniform
        float a0 = 0.f, a1 = 0.f, a2 = 0.f, a3 = 0.f;
#pragma unroll
        for (int k = 0; k < 64; k += 4) {
            const float4 xv = *(const float4*)(&lds_x[nn][k]);  // broadcast
            a0 = fmaf(xv.x, Wc[k],     a0);
            a1 = fmaf(xv.y, Wc[k + 1], a1);
            a2 = fmaf(xv.z, Wc[k + 2], a2);
            a3 = fmaf(xv.w, Wc[k + 3], a3);
        }
        outbuf[(size_t)gn * DO + lane] = (a0 + a1) + (a2 + a3);
    }

    // histogram tail (grid-stride over edges)
    const int gt = blockIdx.x * blockDim.x + t;
    const int nt = gridDim.x * blockDim.x;
    for (int e = gt; e < n_edges; e += nt)
        atomicAdd(&cnt[dst[e]], 1);
}

// ---------------------------------------------------------------------------
// K3a/b/c: parallel exclusive scan (3 phases)
// ---------------------------------------------------------------------------
__global__ void __launch_bounds__(256) scan_partial(
    const int* __restrict__ cnt, int* __restrict__ local,
    int* __restrict__ bsum, int n_nodes)
{
    const int C = (n_nodes + NB - 1) / NB;
    const int t = threadIdx.x, lane = t & 63, w = t >> 6;
    const int i = blockIdx.x * C + t;

    int v = (t < C && i < n_nodes) ? cnt[i] : 0;
    int incl = v;
#pragma unroll
    for (int off = 1; off < 64; off <<= 1) {
        int u = __shfl_up(incl, off, 64);
        if (lane >= off) incl += u;
    }
    __shared__ int ws[4], wo[4];
    if (lane == 63) ws[w] = incl;
    __syncthreads();
    if (t == 0) {
        int r = 0;
#pragma unroll
        for (int q = 0; q < 4; ++q) { wo[q] = r; r += ws[q]; }
        bsum[blockIdx.x] = r;
    }
    __syncthreads();
    if (t < C && i < n_nodes) local[i] = incl - v + wo[w];
}

__global__ void __launch_bounds__(NB) scan_bsum(
    int* __restrict__ bsum, int* __restrict__ row_start, int n_nodes)
{
    const int t = threadIdx.x, lane = t & 63, w = t >> 6;
    int v = bsum[t];
    int incl = v;
#pragma unroll
    for (int off = 1; off < 64; off <<= 1) {
        int u = __shfl_up(incl, off, 64);
        if (lane >= off) incl += u;
    }
    __shared__ int ws[4], wo[4];
    if (lane == 63) ws[w] = incl;
    __syncthreads();
    if (t == 0) {
        int r = 0;
#pragma unroll
        for (int q = 0; q < 4; ++q) { wo[q] = r; r += ws[q]; }
    }
    __syncthreads();
    int excl = incl - v + wo[w];
    bsum[t] = excl;
    if (t == NB - 1) row_start[n_nodes] = excl + v;
}

__global__ void __launch_bounds__(256) scan_add(
    const int* __restrict__ local, const int* __restrict__ bsum,
    int* __restrict__ row_start, int* __restrict__ cursor, int n_nodes)
{
    const int C = (n_nodes + NB - 1) / NB;
    const int i = blockIdx.x * C + threadIdx.x;
    if (threadIdx.x < C && i < n_nodes) {
        int r = local[i] + bsum[blockIdx.x];
        row_start[i] = r;
        cursor[i]    = r;
    }
}

// ---------------------------------------------------------------------------
// K4: scatter (edge_id, src_id, dst_id, 0) int4 records into CSR order.
// 2 edges per thread for ILP on the atomic-return -> store chain.
// ---------------------------------------------------------------------------
__global__ void __launch_bounds__(256) scatter_kernel(
    const int* __restrict__ dst, const int* __restrict__ src,
    int* __restrict__ cursor, int4* __restrict__ csr, int n_edges)
{
    const int half = (n_edges + 1) >> 1;
    const int g = blockIdx.x * blockDim.x + threadIdx.x;
    if (g >= half) return;
    const int e1 = g + half;
    const bool h1 = e1 < n_edges;
    const int d0 = dst[g];
    const int s0 = src[g];
    const int d1 = h1 ? dst[e1] : 0;
    const int s1 = h1 ? src[e1] : 0;
    const int p0 = atomicAdd(&cursor[d0], 1);
    const int p1 = h1 ? atomicAdd(&cursor[d1], 1) : 0;
    csr[p0] = make_int4(g, s0, d0, 0);
    if (h1) csr[p1] = make_int4(e1, s1, d1, 0);
}

// ---------------------------------------------------------------------------
// K5: fused edge-message + segment aggregation (R9 structure).
// CHANGE: edge rows staged as PACKED BF16 (16 dwords/row) -> 4 uniform
// ds_read_b128 per position instead of 8, LDS 8 KB/block. Unpack is
// shift/and + fp32 FMA; W/b/Ps/Pd stay fp32 (error << threshold).
// ---------------------------------------------------------------------------
__global__ void __launch_bounds__(128) agg_tile_kernel(
    const float* __restrict__ edge,
    const float* __restrict__ W_e, const float* __restrict__ b_e,
    const float* __restrict__ Ps, const float* __restrict__ Pd,
    const int* __restrict__ row_start, const int4* __restrict__ csr,
    float* __restrict__ msum, int n_edges)
{
    __shared__ unsigned lds_er[TP][16];   // 8 KB (bf16-packed rows)

    const int t    = threadIdx.x;
    const int lane = t & 63;
    const int wid  = __builtin_amdgcn_readfirstlane((int)(t >> 6));
    const int j0   = blockIdx.x * TP;

    // ---- stage: 128 rows, 8 threads x float4 -> packed uint2 each ----
    {
        const int rr = t >> 3;            // 0..15
        const int c4 = (t & 7) << 2;      // float col 0,4,...,28
#pragma unroll
        for (int p = 0; p < 8; ++p) {
            const int row = p * 16 + rr;
            const int j   = j0 + row;
            const int e   = (j < n_edges) ? csr[j].x : 0;
            const float4 v = *(const float4*)(edge + (size_t)e * DE + c4);
            const uint2 pk = make_uint2(pack_bf16(v.x, v.y), pack_bf16(v.z, v.w));
            *(uint2*)(&lds_er[row][c4 >> 1]) = pk;
        }
    }

    float Wm[32];
#pragma unroll
    for (int k = 0; k < 32; ++k)
        Wm[k] = W_e[(64 + k) * DO + lane];
    const float bj = b_e[lane];

    const int wbeg = j0 + wid * 64;
    const int wcnt = min(n_edges - wbeg, 64);

    int4 my4 = make_int4(0, 0, -1, 0);
    if (wcnt > 0) my4 = csr[min(wbeg + lane, n_edges - 1)];

    __syncthreads();
    if (wcnt <= 0) return;

    float acc = 0.f, bpd = 0.f;
    int cur_d = -1;

#define EDGE_FMA(lp_expr)                                                     \
    {                                                                         \
        const uint4* __restrict__ lrow = (const uint4*)&lds_er[(lp_expr)][0]; \
        float m0 = bpd + pcq, m1 = 0.f, m2 = 0.f, m3 = 0.f;                   \
        _Pragma("unroll")                                                     \
        for (int kk = 0; kk < 4; ++kk) {                                      \
            const uint4 u = lrow[kk];                                         \
            m0 = fmaf(__uint_as_float(u.x << 16),          Wm[kk*8+0], m0);   \
            m1 = fmaf(__uint_as_float(u.x & 0xffff0000u),  Wm[kk*8+1], m1);   \
            m2 = fmaf(__uint_as_float(u.y << 16),          Wm[kk*8+2], m2);   \
            m3 = fmaf(__uint_as_float(u.y & 0xffff0000u),  Wm[kk*8+3], m3);   \
            m0 = fmaf(__uint_as_float(u.z << 16),          Wm[kk*8+4], m0);   \
            m1 = fmaf(__uint_as_float(u.z & 0xffff0000u),  Wm[kk*8+5], m1);   \
            m2 = fmaf(__uint_as_float(u.w << 16),          Wm[kk*8+6], m2);   \
            m3 = fmaf(__uint_as_float(u.w & 0xffff0000u),  Wm[kk*8+7], m3);   \
        }                                                                     \
        acc += fmaxf((m0 + m1) + (m2 + m3), 0.f);                             \
    }

    if (wcnt == 64) {
        // ---------------- fast path: full window ----------------
        float pn[CH];
#pragma unroll
        for (int q = 0; q < CH; ++q) {
            const int s = __builtin_amdgcn_readlane(my4.y, q);
            pn[q] = Ps[(unsigned)s * DO + lane];
        }
#pragma unroll
        for (int c = 0; c < 64; c += CH) {
            float pc[CH];
#pragma unroll
            for (int q = 0; q < CH; ++q) pc[q] = pn[q];
            if (c + CH < 64) {
#pragma unroll
                for (int q = 0; q < CH; ++q) {
                    const int s = __builtin_amdgcn_readlane(my4.y, c + CH + q);
                    pn[q] = Ps[(unsigned)s * DO + lane];
                }
            }
#pragma unroll
            for (int q = 0; q < CH; ++q) {
                const int p = c + q;
                const int d = __builtin_amdgcn_readlane(my4.z, p);
                if (d != cur_d) {
                    if (cur_d >= 0) {
                        if (row_start[cur_d] >= wbeg)
                            msum[(size_t)cur_d * DO + lane] = acc;
                        else
                            unsafeAtomicAdd(&msum[(size_t)cur_d * DO + lane], acc);
                    }
                    acc = 0.f;
                    cur_d = d;
                    bpd = bj + Pd[(unsigned)d * DO + lane];
                }
                const float pcq = pc[q];
                EDGE_FMA(wid * 64 + p)
            }
        }
    } else {
        // ---------------- generic tail path ----------------
        float pn[CH];
#pragma unroll
        for (int q = 0; q < CH; ++q) {
            const int s = __builtin_amdgcn_readlane(my4.y, min(q, wcnt - 1));
            pn[q] = Ps[(unsigned)s * DO + lane];
        }
        for (int c = 0; c < wcnt; c += CH) {
            float pc[CH];
#pragma unroll
            for (int q = 0; q < CH; ++q) pc[q] = pn[q];
#pragma unroll
            for (int q = 0; q < CH; ++q) {
                const int s = __builtin_amdgcn_readlane(my4.y, min(c + CH + q, wcnt - 1));
                pn[q] = Ps[(unsigned)s * DO + lane];
            }
#pragma unroll
            for (int q = 0; q < CH; ++q) {
                const int p = c + q;
                if (p < wcnt) {
                    const int d = __builtin_amdgcn_readlane(my4.z, p);
                    if (d != cur_d) {
                        if (cur_d >= 0) {
                            if (row_start[cur_d] >= wbeg)
                                msum[(size_t)cur_d * DO + lane] = acc;
                            else
                                unsafeAtomicAdd(&msum[(size_t)cur_d * DO + lane], acc);
                        }
                        acc = 0.f;
                        cur_d = d;
                        bpd = bj + Pd[(unsigned)d * DO + lane];
                    }
                    const float pcq = pc[q];
                    EDGE_FMA(wid * 64 + p)
                }
            }
        }
    }
#undef EDGE_FMA

    {   // final flush
        const int sb = row_start[cur_d];
        const int se = row_start[cur_d + 1];
        if (sb >= wbeg && se <= wbeg + wcnt)
            msum[(size_t)cur_d * DO + lane] = acc;
        else
            unsafeAtomicAdd(&msum[(size_t)cur_d * DO + lane], acc);
    }
}

// ---------------------------------------------------------------------------
// K6: tiled node update. Stage msum + node 64-row tiles into LDS; waves 0,1
// compute A = msum@Wt (nodes 0-31 / 32-63), waves 2,3 B = node@Wb; partials
// written back into the staging LDS; combine pass applies /deg, bias, relu.
// ---------------------------------------------------------------------------
__global__ void __launch_bounds__(256) node_out_kernel(
    const float* __restrict__ node, const float* __restrict__ msum,
    const int* __restrict__ row_start,
    const float* __restrict__ W_v, const float* __restrict__ b_v,
    float* __restrict__ out, int n_nodes)
{
    __shared__ float lds_a[64][64];   // msum rows -> A partial
    __shared__ float lds_b[64][64];   // node rows -> B partial

    const int t    = threadIdx.x;
    const int lane = t & 63;
    const int w    = __builtin_amdgcn_readfirstlane((int)(t >> 6));
    const int nbase = blockIdx.x * 64;

#pragma unroll
    for (int q = 0; q < 4; ++q) {
        const int f4 = q * 256 + t;
        const int nn = f4 >> 4;
        const int cc = (f4 & 15) << 2;
        const int gn = nbase + nn;
        float4 va = make_float4(0.f, 0.f, 0.f, 0.f);
        float4 vb = va;
        if (gn < n_nodes) {
            va = *(const float4*)(msum + (size_t)gn * DO + cc);
            vb = *(const float4*)(node + (size_t)gn * DN + cc);
        }
        *(float4*)(&lds_a[nn][cc]) = va;
        *(float4*)(&lds_b[nn][cc]) = vb;
    }

    float Wc[64];
    const int wrow0 = (w < 2) ? 0 : 64;      // Wt rows 0..63 | Wb rows 64..127
#pragma unroll
    for (int k = 0; k < 64; ++k)
        Wc[k] = W_v[(wrow0 + k) * DO + lane];
    const int nodes0 = (w & 1) * 32;

    __syncthreads();

    {
        float (* __restrict__ tile)[64] = (w < 2) ? lds_a : lds_b;
        for (int i = 0; i < 32; ++i) {
            const int nn = nodes0 + i;
            const int gn = nbase + nn;
            if (gn >= n_nodes) break;        // wave-uniform
            float a0 = 0.f, a1 = 0.f, a2 = 0.f, a3 = 0.f;
#pragma unroll
            for (int k = 0; k < 64; k += 4) {
                const float4 xv = *(const float4*)(&tile[nn][k]);
                a0 = fmaf(xv.x, Wc[k],     a0);
                a1 = fmaf(xv.y, Wc[k + 1], a1);
                a2 = fmaf(xv.z, Wc[k + 2], a2);
                a3 = fmaf(xv.w, Wc[k + 3], a3);
            }
            tile[nn][lane] = (a0 + a1) + (a2 + a3);   // whole wave done reading row nn
        }
    }

    __syncthreads();

    const float bj = b_v[lane];
#pragma unroll
    for (int q = 0; q < 16; ++q) {
        const int idx = q * 256 + t;         // 0..4095
        const int nn  = idx >> 6;
        const int gn  = nbase + nn;
        if (gn < n_nodes) {
            const float dg = (float)(row_start[gn + 1] - row_start[gn]);
            const float neigh = (dg > 0.f) ? lds_a[nn][lane] / dg : 0.f;
            out[(size_t)gn * DO + lane] = fmaxf(neigh + lds_b[nn][lane] + bj, 0.f);
        }
    }
}

extern "C" void kernel_launch(void* const* d_in, const int* in_sizes, int n_in,
                              void* d_out, int out_size, void* d_ws, size_t ws_size,
                              hipStream_t stream)
{
    const float* node = (const float*)d_in[0];
    const float* edge = (const float*)d_in[1];
    const int*   src  = (const int*)d_in[2];
    const int*   dst  = (const int*)d_in[3];
    const float* W_e  = (const float*)d_in[4];
    const float* b_e  = (const float*)d_in[5];
    const float* W_v  = (const float*)d_in[6];
    const float* b_v  = (const float*)d_in[7];
    float* out = (float*)d_out;

    const int n_nodes = in_sizes[0] / DN;
    const int n_edges = in_sizes[2];
    const int ntiles  = (n_nodes + 63) / 64;

    // Workspace: Ps | Pd | msum (floats) | row_start | cnt | cursor | local | bsum | csr(int4)
    float* Ps   = (float*)d_ws;
    float* Pd   = Ps   + (size_t)n_nodes * DO;
    float* msum = Pd   + (size_t)n_nodes * DO;
    int* row_start = (int*)(msum + (size_t)n_nodes * DO);
    int* cnt       = row_start + (n_nodes + 1);
    int* cursor    = cnt + n_nodes;
    int* local     = cursor + n_nodes;
    int* bsum      = local + n_nodes;
    int4* csr      = (int4*)(((size_t)(bsum + NB) + 15) & ~(size_t)15);

    hipMemsetAsync(msum, 0, (size_t)n_nodes * DO * sizeof(float), stream);
    hipMemsetAsync(cnt, 0, (size_t)n_nodes * sizeof(int), stream);

    pre_hist_kernel<<<ntiles, 256, 0, stream>>>(node, W_e, dst, Ps, Pd, cnt,
                                                n_nodes, n_edges);
    scan_partial<<<NB, 256, 0, stream>>>(cnt, local, bsum, n_nodes);
    scan_bsum<<<1, NB, 0, stream>>>(bsum, row_start, n_nodes);
    scan_add<<<NB, 256, 0, stream>>>(local, bsum, row_start, cursor, n_nodes);
    scatter_kernel<<<((n_edges + 1) / 2 + 255) / 256, 256, 0, stream>>>(dst, src, cursor, csr, n_edges);
    agg_tile_kernel<<<(n_edges + TP - 1) / TP, 128, 0, stream>>>(edge, W_e, b_e, Ps, Pd,
                                                                 row_start, csr, msum, n_edges);
    node_out_kernel<<<ntiles, 256, 0, stream>>>(node, msum, row_start, W_v, b_v,
                                                out, n_nodes);
}

// Round 11
// 209.946 us; speedup vs baseline: 1.8999x; 1.2499x over previous
//
#include <hip/hip_runtime.h>

#define DN 64
#define DE 32
#define DO 64
#define NB 256   // scan phase-1 blocks (requires n_nodes <= NB*256)
#define TP 128   // CSR positions per agg block (2 waves x 64)
#define CH 8     // Ps prefetch chunk (double-buffered)

typedef __attribute__((ext_vector_type(8))) short bf16x8;
typedef __attribute__((ext_vector_type(4))) float f32x4;

__device__ inline unsigned pack_bf16(float a, float b) {
    unsigned ua = __float_as_uint(a), ub = __float_as_uint(b);
    ua = (ua + 0x7fffu + ((ua >> 16) & 1u)) >> 16;     // RNE bf16
    ub = (ub + 0x7fffu + ((ub >> 16) & 1u)) >> 16;
    return ua | (ub << 16);
}

// ---------------------------------------------------------------------------
// K1: tiled per-node projections + degree histogram (unchanged from R10).
// ---------------------------------------------------------------------------
__global__ void __launch_bounds__(256) pre_hist_kernel(
    const float* __restrict__ node, const float* __restrict__ W_e,
    const int* __restrict__ dst,
    float* __restrict__ Ps, float* __restrict__ Pd,
    int* __restrict__ cnt, int n_nodes, int n_edges)
{
    __shared__ float lds_x[64][64];   // 16 KB

    const int t    = threadIdx.x;
    const int lane = t & 63;
    const int w    = __builtin_amdgcn_readfirstlane((int)(t >> 6));
    const int nbase = blockIdx.x * 64;

#pragma unroll
    for (int q = 0; q < 4; ++q) {
        const int f4 = q * 256 + t;
        const int nn = f4 >> 4;
        const int cc = (f4 & 15) << 2;
        const int gn = nbase + nn;
        float4 v = make_float4(0.f, 0.f, 0.f, 0.f);
        if (gn < n_nodes) v = *(const float4*)(node + (size_t)gn * DN + cc);
        *(float4*)(&lds_x[nn][cc]) = v;
    }

    float Wc[64];
    const int wrow0 = (w < 2) ? 0 : 96;
#pragma unroll
    for (int k = 0; k < 64; ++k)
        Wc[k] = W_e[(wrow0 + k) * DO + lane];
    float* __restrict__ outbuf = (w < 2) ? Ps : Pd;
    const int nodes0 = (w & 1) * 32;

    __syncthreads();

    for (int i = 0; i < 32; ++i) {
        const int nn = nodes0 + i;
        const int gn = nbase + nn;
        if (gn >= n_nodes) break;
        float a0 = 0.f, a1 = 0.f, a2 = 0.f, a3 = 0.f;
#pragma unroll
        for (int k = 0; k < 64; k += 4) {
            const float4 xv = *(const float4*)(&lds_x[nn][k]);
            a0 = fmaf(xv.x, Wc[k],     a0);
            a1 = fmaf(xv.y, Wc[k + 1], a1);
            a2 = fmaf(xv.z, Wc[k + 2], a2);
            a3 = fmaf(xv.w, Wc[k + 3], a3);
        }
        outbuf[(size_t)gn * DO + lane] = (a0 + a1) + (a2 + a3);
    }

    const int gt = blockIdx.x * blockDim.x + t;
    const int nt = gridDim.x * blockDim.x;
    for (int e = gt; e < n_edges; e += nt)
        atomicAdd(&cnt[dst[e]], 1);
}

// ---------------------------------------------------------------------------
// K3a/b/c: parallel exclusive scan (3 phases, unchanged)
// ---------------------------------------------------------------------------
__global__ void __launch_bounds__(256) scan_partial(
    const int* __restrict__ cnt, int* __restrict__ local,
    int* __restrict__ bsum, int n_nodes)
{
    const int C = (n_nodes + NB - 1) / NB;
    const int t = threadIdx.x, lane = t & 63, w = t >> 6;
    const int i = blockIdx.x * C + t;

    int v = (t < C && i < n_nodes) ? cnt[i] : 0;
    int incl = v;
#pragma unroll
    for (int off = 1; off < 64; off <<= 1) {
        int u = __shfl_up(incl, off, 64);
        if (lane >= off) incl += u;
    }
    __shared__ int ws[4], wo[4];
    if (lane == 63) ws[w] = incl;
    __syncthreads();
    if (t == 0) {
        int r = 0;
#pragma unroll
        for (int q = 0; q < 4; ++q) { wo[q] = r; r += ws[q]; }
        bsum[blockIdx.x] = r;
    }
    __syncthreads();
    if (t < C && i < n_nodes) local[i] = incl - v + wo[w];
}

__global__ void __launch_bounds__(NB) scan_bsum(
    int* __restrict__ bsum, int* __restrict__ row_start, int n_nodes)
{
    const int t = threadIdx.x, lane = t & 63, w = t >> 6;
    int v = bsum[t];
    int incl = v;
#pragma unroll
    for (int off = 1; off < 64; off <<= 1) {
        int u = __shfl_up(incl, off, 64);
        if (lane >= off) incl += u;
    }
    __shared__ int ws[4], wo[4];
    if (lane == 63) ws[w] = incl;
    __syncthreads();
    if (t == 0) {
        int r = 0;
#pragma unroll
        for (int q = 0; q < 4; ++q) { wo[q] = r; r += ws[q]; }
    }
    __syncthreads();
    int excl = incl - v + wo[w];
    bsum[t] = excl;
    if (t == NB - 1) row_start[n_nodes] = excl + v;
}

__global__ void __launch_bounds__(256) scan_add(
    const int* __restrict__ local, const int* __restrict__ bsum,
    int* __restrict__ row_start, int* __restrict__ cursor, int n_nodes)
{
    const int C = (n_nodes + NB - 1) / NB;
    const int i = blockIdx.x * C + threadIdx.x;
    if (threadIdx.x < C && i < n_nodes) {
        int r = local[i] + bsum[blockIdx.x];
        row_start[i] = r;
        cursor[i]    = r;
    }
}

// ---------------------------------------------------------------------------
// K4: scatter (edge_id, src_id, dst_id, 0) int4 records into CSR order.
// ---------------------------------------------------------------------------
__global__ void __launch_bounds__(256) scatter_kernel(
    const int* __restrict__ dst, const int* __restrict__ src,
    int* __restrict__ cursor, int4* __restrict__ csr, int n_edges)
{
    const int half = (n_edges + 1) >> 1;
    const int g = blockIdx.x * blockDim.x + threadIdx.x;
    if (g >= half) return;
    const int e1 = g + half;
    const bool h1 = e1 < n_edges;
    const int d0 = dst[g];
    const int s0 = src[g];
    const int d1 = h1 ? dst[e1] : 0;
    const int s1 = h1 ? src[e1] : 0;
    const int p0 = atomicAdd(&cursor[d0], 1);
    const int p1 = h1 ? atomicAdd(&cursor[d1], 1) : 0;
    csr[p0] = make_int4(g, s0, d0, 0);
    if (h1) csr[p1] = make_int4(e1, s1, d1, 0);
}

// ---------------------------------------------------------------------------
// K5: MFMA edge-message + segment aggregation. Per wave (64 CSR positions):
//   1. A-frags built straight from global edge rows (shfl edge id, 2xfloat4,
//      bf16-pack): lane holds row (lane&15), k = 8*(lane>>4)+0..7.
//   2. B-frags = Wm(32x64) bf16, preloaded: lane holds col (lane&15),
//      k = 8*(lane>>4)+0..7, per N-tile.
//   3. 16x mfma_f32_16x16x32_bf16 -> D[64 edges][64 cols] raw scores in the
//      verified C/D layout (col=lane&15, row=(lane>>4)*4+reg).
//   4. D packed bf16 (row pairs) into LDS [32][68] (padded: 2-way banks max).
//   5. Segment walk (unchanged logic): lane=col, per position read M from
//      LDS, add Ps[src]+Pd[dst]+b, relu, accumulate; interior segments plain
//      store, window-spanning ones unsafeAtomicAdd.
// All LDS traffic is same-wave -> NO barriers anywhere.
// ---------------------------------------------------------------------------
__global__ void __launch_bounds__(128) agg_mfma_kernel(
    const float* __restrict__ edge,
    const float* __restrict__ W_e, const float* __restrict__ b_e,
    const float* __restrict__ Ps, const float* __restrict__ Pd,
    const int* __restrict__ row_start, const int4* __restrict__ csr,
    float* __restrict__ msum, int n_edges)
{
    __shared__ unsigned lds_m[2][32][68];   // 17.4 KB: bf16-paired raw scores

    const int t    = threadIdx.x;
    const int lane = t & 63;
    const int wid  = __builtin_amdgcn_readfirstlane((int)(t >> 6));
    const int wbeg = blockIdx.x * TP + wid * 64;
    const int wcnt = min(n_edges - wbeg, 64);
    if (wcnt <= 0) return;                  // no barriers in kernel: safe

    const int l15 = lane & 15;
    const int k0  = (lane >> 4) << 3;       // k-offset 0/8/16/24

    // ---- B fragments (Wm bf16), one per N-tile ----
    union { unsigned u[4]; bf16x8 v; } bfr[4];
#pragma unroll
    for (int Nt = 0; Nt < 4; ++Nt) {
        const int col = (Nt << 4) | l15;
        float wv[8];
#pragma unroll
        for (int e = 0; e < 8; ++e)
            wv[e] = W_e[(64 + k0 + e) * DO + col];
#pragma unroll
        for (int v2 = 0; v2 < 4; ++v2)
            bfr[Nt].u[v2] = pack_bf16(wv[2 * v2], wv[2 * v2 + 1]);
    }
    const float bj = b_e[lane];

    const int4 my4 = csr[min(wbeg + lane, n_edges - 1)];

    // ---- MFMA: D = er(64x32) @ Wm(32x64), K=32 in one step ----
#pragma unroll
    for (int Mt = 0; Mt < 4; ++Mt) {
        const int eA = __shfl(my4.x, (Mt << 4) | l15, 64);
        const float* __restrict__ ep = edge + (size_t)(unsigned)eA * DE + k0;
        const float4 f0 = *(const float4*)(ep);
        const float4 f1 = *(const float4*)(ep + 4);
        union { unsigned u[4]; bf16x8 v; } afr;
        afr.u[0] = pack_bf16(f0.x, f0.y);
        afr.u[1] = pack_bf16(f0.z, f0.w);
        afr.u[2] = pack_bf16(f1.x, f1.y);
        afr.u[3] = pack_bf16(f1.z, f1.w);
        const int rp0 = (Mt << 3) + ((lane >> 4) << 1);
#pragma unroll
        for (int Nt = 0; Nt < 4; ++Nt) {
            f32x4 dz = {0.f, 0.f, 0.f, 0.f};
            f32x4 d = __builtin_amdgcn_mfma_f32_16x16x32_bf16(afr.v, bfr[Nt].v, dz, 0, 0, 0);
            const int col = (Nt << 4) | l15;
            lds_m[wid][rp0][col]     = pack_bf16(d[0], d[1]);   // rows R0,R0+1
            lds_m[wid][rp0 + 1][col] = pack_bf16(d[2], d[3]);   // rows R0+2,R0+3
        }
    }
    // same-wave LDS write->read below; compiler inserts lgkmcnt waits

    // ---- segment walk: lane owns output column `lane` ----
    float acc = 0.f, bpd = 0.f;
    int cur_d = -1;

    if (wcnt == 64) {
        float pn[CH];
#pragma unroll
        for (int q = 0; q < CH; ++q) {
            const int s = __builtin_amdgcn_readlane(my4.y, q);
            pn[q] = Ps[(unsigned)s * DO + lane];
        }
#pragma unroll
        for (int c = 0; c < 64; c += CH) {
            float pc[CH];
#pragma unroll
            for (int q = 0; q < CH; ++q) pc[q] = pn[q];
            if (c + CH < 64) {
#pragma unroll
                for (int q = 0; q < CH; ++q) {
                    const int s = __builtin_amdgcn_readlane(my4.y, c + CH + q);
                    pn[q] = Ps[(unsigned)s * DO + lane];
                }
            }
            unsigned um[4];
#pragma unroll
            for (int h = 0; h < 4; ++h)
                um[h] = lds_m[wid][(c >> 1) + h][lane];
#pragma unroll
            for (int q = 0; q < CH; ++q) {
                const int p = c + q;
                const int d = __builtin_amdgcn_readlane(my4.z, p);
                if (d != cur_d) {
                    if (cur_d >= 0) {
                        if (row_start[cur_d] >= wbeg)
                            msum[(size_t)cur_d * DO + lane] = acc;
                        else
                            unsafeAtomicAdd(&msum[(size_t)cur_d * DO + lane], acc);
                    }
                    acc = 0.f;
                    cur_d = d;
                    bpd = bj + Pd[(unsigned)d * DO + lane];
                }
                const unsigned u = um[q >> 1];
                const float mv = (q & 1) ? __uint_as_float(u & 0xffff0000u)
                                         : __uint_as_float(u << 16);
                acc += fmaxf(mv + bpd + pc[q], 0.f);
            }
        }
    } else {
        // generic tail (last partial window)
        for (int p = 0; p < wcnt; ++p) {
            const int d = __builtin_amdgcn_readlane(my4.z, p);
            const int s = __builtin_amdgcn_readlane(my4.y, p);
            const float ps = Ps[(unsigned)s * DO + lane];
            if (d != cur_d) {
                if (cur_d >= 0) {
                    if (row_start[cur_d] >= wbeg)
                        msum[(size_t)cur_d * DO + lane] = acc;
                    else
                        unsafeAtomicAdd(&msum[(size_t)cur_d * DO + lane], acc);
                }
                acc = 0.f;
                cur_d = d;
                bpd = bj + Pd[(unsigned)d * DO + lane];
            }
            const unsigned u = lds_m[wid][p >> 1][lane];
            const float mv = (p & 1) ? __uint_as_float(u & 0xffff0000u)
                                     : __uint_as_float(u << 16);
            acc += fmaxf(mv + bpd + ps, 0.f);
        }
    }

    {   // final flush
        const int sb = row_start[cur_d];
        const int se = row_start[cur_d + 1];
        if (sb >= wbeg && se <= wbeg + wcnt)
            msum[(size_t)cur_d * DO + lane] = acc;
        else
            unsafeAtomicAdd(&msum[(size_t)cur_d * DO + lane], acc);
    }
}

// ---------------------------------------------------------------------------
// K6: tiled node update (unchanged from R10).
// ---------------------------------------------------------------------------
__global__ void __launch_bounds__(256) node_out_kernel(
    const float* __restrict__ node, const float* __restrict__ msum,
    const int* __restrict__ row_start,
    const float* __restrict__ W_v, const float* __restrict__ b_v,
    float* __restrict__ out, int n_nodes)
{
    __shared__ float lds_a[64][64];
    __shared__ float lds_b[64][64];

    const int t    = threadIdx.x;
    const int lane = t & 63;
    const int w    = __builtin_amdgcn_readfirstlane((int)(t >> 6));
    const int nbase = blockIdx.x * 64;

#pragma unroll
    for (int q = 0; q < 4; ++q) {
        const int f4 = q * 256 + t;
        const int nn = f4 >> 4;
        const int cc = (f4 & 15) << 2;
        const int gn = nbase + nn;
        float4 va = make_float4(0.f, 0.f, 0.f, 0.f);
        float4 vb = va;
        if (gn < n_nodes) {
            va = *(const float4*)(msum + (size_t)gn * DO + cc);
            vb = *(const float4*)(node + (size_t)gn * DN + cc);
        }
        *(float4*)(&lds_a[nn][cc]) = va;
        *(float4*)(&lds_b[nn][cc]) = vb;
    }

    float Wc[64];
    const int wrow0 = (w < 2) ? 0 : 64;
#pragma unroll
    for (int k = 0; k < 64; ++k)
        Wc[k] = W_v[(wrow0 + k) * DO + lane];
    const int nodes0 = (w & 1) * 32;

    __syncthreads();

    {
        float (* __restrict__ tile)[64] = (w < 2) ? lds_a : lds_b;
        for (int i = 0; i < 32; ++i) {
            const int nn = nodes0 + i;
            const int gn = nbase + nn;
            if (gn >= n_nodes) break;
            float a0 = 0.f, a1 = 0.f, a2 = 0.f, a3 = 0.f;
#pragma unroll
            for (int k = 0; k < 64; k += 4) {
                const float4 xv = *(const float4*)(&tile[nn][k]);
                a0 = fmaf(xv.x, Wc[k],     a0);
                a1 = fmaf(xv.y, Wc[k + 1], a1);
                a2 = fmaf(xv.z, Wc[k + 2], a2);
                a3 = fmaf(xv.w, Wc[k + 3], a3);
            }
            tile[nn][lane] = (a0 + a1) + (a2 + a3);
        }
    }

    __syncthreads();

    const float bj = b_v[lane];
#pragma unroll
    for (int q = 0; q < 16; ++q) {
        const int idx = q * 256 + t;
        const int nn  = idx >> 6;
        const int gn  = nbase + nn;
        if (gn < n_nodes) {
            const float dg = (float)(row_start[gn + 1] - row_start[gn]);
            const float neigh = (dg > 0.f) ? lds_a[nn][lane] / dg : 0.f;
            out[(size_t)gn * DO + lane] = fmaxf(neigh + lds_b[nn][lane] + bj, 0.f);
        }
    }
}

extern "C" void kernel_launch(void* const* d_in, const int* in_sizes, int n_in,
                              void* d_out, int out_size, void* d_ws, size_t ws_size,
                              hipStream_t stream)
{
    const float* node = (const float*)d_in[0];
    const float* edge = (const float*)d_in[1];
    const int*   src  = (const int*)d_in[2];
    const int*   dst  = (const int*)d_in[3];
    const float* W_e  = (const float*)d_in[4];
    const float* b_e  = (const float*)d_in[5];
    const float* W_v  = (const float*)d_in[6];
    const float* b_v  = (const float*)d_in[7];
    float* out = (float*)d_out;

    const int n_nodes = in_sizes[0] / DN;
    const int n_edges = in_sizes[2];
    const int ntiles  = (n_nodes + 63) / 64;

    // Workspace: Ps | Pd | msum (floats) | row_start | cnt | cursor | local | bsum | csr(int4)
    float* Ps   = (float*)d_ws;
    float* Pd   = Ps   + (size_t)n_nodes * DO;
    float* msum = Pd   + (size_t)n_nodes * DO;
    int* row_start = (int*)(msum + (size_t)n_nodes * DO);
    int* cnt       = row_start + (n_nodes + 1);
    int* cursor    = cnt + n_nodes;
    int* local     = cursor + n_nodes;
    int* bsum      = local + n_nodes;
    int4* csr      = (int4*)(((size_t)(bsum + NB) + 15) & ~(size_t)15);

    hipMemsetAsync(msum, 0, (size_t)n_nodes * DO * sizeof(float), stream);
    hipMemsetAsync(cnt, 0, (size_t)n_nodes * sizeof(int), stream);

    pre_hist_kernel<<<ntiles, 256, 0, stream>>>(node, W_e, dst, Ps, Pd, cnt,
                                                n_nodes, n_edges);
    scan_partial<<<NB, 256, 0, stream>>>(cnt, local, bsum, n_nodes);
    scan_bsum<<<1, NB, 0, stream>>>(bsum, row_start, n_nodes);
    scan_add<<<NB, 256, 0, stream>>>(local, bsum, row_start, cursor, n_nodes);
    scatter_kernel<<<((n_edges + 1) / 2 + 255) / 256, 256, 0, stream>>>(dst, src, cursor, csr, n_edges);
    agg_mfma_kernel<<<(n_edges + TP - 1) / TP, 128, 0, stream>>>(edge, W_e, b_e, Ps, Pd,
                                                                 row_start, csr, msum, n_edges);
    node_out_kernel<<<ntiles, 256, 0, stream>>>(node, msum, row_start, W_v, b_v,
                                                out, n_nodes);
}

// Round 12
// 180.228 us; speedup vs baseline: 2.2132x; 1.1649x over previous
//
#include <hip/hip_runtime.h>

#define DN 64
#define DE 32
#define DO 64
#define NB 256   // scan phase-1 blocks (requires n_nodes <= NB*256)
#define TP 128   // CSR positions per agg block (2 waves x 64)
#define CH 8     // Ps prefetch chunk (double-buffered)

typedef __attribute__((ext_vector_type(8))) short bf16x8;
typedef __attribute__((ext_vector_type(4))) float f32x4;

__device__ inline unsigned pack_bf16(float a, float b) {
    unsigned ua = __float_as_uint(a), ub = __float_as_uint(b);
    ua = (ua + 0x7fffu + ((ua >> 16) & 1u)) >> 16;     // RNE bf16
    ub = (ub + 0x7fffu + ((ub >> 16) & 1u)) >> 16;
    return ua | (ub << 16);
}

union bfu { unsigned u[4]; bf16x8 v; };

// ---------------------------------------------------------------------------
// K1: MFMA per-node projections + degree histogram.
// Ps = node @ W_e[0:64], Pd = node @ W_e[96:160] as dense GEMM tiles:
// block = 64 rows, wave w owns rows w*16..w*16+15. A-frags direct from
// global (lane: row=l15, k=(lane>>4)*8+e); B-frags per N-tile/k-step in
// registers. 16 MFMA per wave replaces 2048 VALU FMAs. No LDS, no barriers.
// ---------------------------------------------------------------------------
__global__ void __launch_bounds__(256) pre_hist_kernel(
    const float* __restrict__ node, const float* __restrict__ W_e,
    const int* __restrict__ dst,
    float* __restrict__ Ps, float* __restrict__ Pd,
    int* __restrict__ cnt, int n_nodes, int n_edges)
{
    const int t    = threadIdx.x;
    const int lane = t & 63;
    const int w    = __builtin_amdgcn_readfirstlane((int)(t >> 6));
    const int l15  = lane & 15;
    const int k0   = (lane >> 4) << 3;

    bfu bS[4][2], bD[4][2];
#pragma unroll
    for (int Nt = 0; Nt < 4; ++Nt) {
        const int col = (Nt << 4) | l15;
#pragma unroll
        for (int ks = 0; ks < 2; ++ks) {
            float ws[8], wd[8];
#pragma unroll
            for (int e = 0; e < 8; ++e) {
                ws[e] = W_e[(ks * 32 + k0 + e) * DO + col];
                wd[e] = W_e[(96 + ks * 32 + k0 + e) * DO + col];
            }
#pragma unroll
            for (int q = 0; q < 4; ++q) {
                bS[Nt][ks].u[q] = pack_bf16(ws[2 * q], ws[2 * q + 1]);
                bD[Nt][ks].u[q] = pack_bf16(wd[2 * q], wd[2 * q + 1]);
            }
        }
    }

    const int row0 = blockIdx.x * 64 + w * 16;
    if (row0 < n_nodes) {
        bfu aF[2];
#pragma unroll
        for (int ks = 0; ks < 2; ++ks) {
            const int r = min(row0 + l15, n_nodes - 1);
            const float* __restrict__ p = node + (size_t)r * DN + ks * 32 + k0;
            const float4 f0 = *(const float4*)p;
            const float4 f1 = *(const float4*)(p + 4);
            aF[ks].u[0] = pack_bf16(f0.x, f0.y);
            aF[ks].u[1] = pack_bf16(f0.z, f0.w);
            aF[ks].u[2] = pack_bf16(f1.x, f1.y);
            aF[ks].u[3] = pack_bf16(f1.z, f1.w);
        }
        const int rb = row0 + ((lane >> 4) << 2);
#pragma unroll
        for (int Nt = 0; Nt < 4; ++Nt) {
            const f32x4 z = {0.f, 0.f, 0.f, 0.f};
            f32x4 aS = __builtin_amdgcn_mfma_f32_16x16x32_bf16(aF[0].v, bS[Nt][0].v, z, 0, 0, 0);
            aS = __builtin_amdgcn_mfma_f32_16x16x32_bf16(aF[1].v, bS[Nt][1].v, aS, 0, 0, 0);
            f32x4 aD = __builtin_amdgcn_mfma_f32_16x16x32_bf16(aF[0].v, bD[Nt][0].v, z, 0, 0, 0);
            aD = __builtin_amdgcn_mfma_f32_16x16x32_bf16(aF[1].v, bD[Nt][1].v, aD, 0, 0, 0);
            const int col = (Nt << 4) | l15;
#pragma unroll
            for (int r = 0; r < 4; ++r) {
                if (rb + r < n_nodes) {
                    Ps[(size_t)(rb + r) * DO + col] = aS[r];
                    Pd[(size_t)(rb + r) * DO + col] = aD[r];
                }
            }
        }
    }

    // histogram (grid-stride over edges)
    const int gt = blockIdx.x * blockDim.x + t;
    const int nt = gridDim.x * blockDim.x;
    for (int e = gt; e < n_edges; e += nt)
        atomicAdd(&cnt[dst[e]], 1);
}

// ---------------------------------------------------------------------------
// K3a: per-block local exclusive scan + block sums (unchanged)
// ---------------------------------------------------------------------------
__global__ void __launch_bounds__(256) scan_partial(
    const int* __restrict__ cnt, int* __restrict__ local,
    int* __restrict__ bsum, int n_nodes)
{
    const int C = (n_nodes + NB - 1) / NB;
    const int t = threadIdx.x, lane = t & 63, w = t >> 6;
    const int i = blockIdx.x * C + t;

    int v = (t < C && i < n_nodes) ? cnt[i] : 0;
    int incl = v;
#pragma unroll
    for (int off = 1; off < 64; off <<= 1) {
        int u = __shfl_up(incl, off, 64);
        if (lane >= off) incl += u;
    }
    __shared__ int ws[4], wo[4];
    if (lane == 63) ws[w] = incl;
    __syncthreads();
    if (t == 0) {
        int r = 0;
#pragma unroll
        for (int q = 0; q < 4; ++q) { wo[q] = r; r += ws[q]; }
        bsum[blockIdx.x] = r;
    }
    __syncthreads();
    if (t < C && i < n_nodes) local[i] = incl - v + wo[w];
}

// ---------------------------------------------------------------------------
// K3b: merged bsum-scan + add. Every block redundantly scans the NB block
// sums in-registers (cheap), picks its own offset, applies to its chunk.
// Saves one launch + its serialization vs the old scan_bsum/scan_add pair.
// ---------------------------------------------------------------------------
__global__ void __launch_bounds__(256) scan_final(
    const int* __restrict__ local, const int* __restrict__ bsum,
    int* __restrict__ row_start, int* __restrict__ cursor, int n_nodes)
{
    const int t = threadIdx.x, lane = t & 63, w = t >> 6;
    int v = bsum[t];
    int incl = v;
#pragma unroll
    for (int off = 1; off < 64; off <<= 1) {
        int u = __shfl_up(incl, off, 64);
        if (lane >= off) incl += u;
    }
    __shared__ int ws[4], wo[4];
    if (lane == 63) ws[w] = incl;
    __syncthreads();
    if (t == 0) {
        int r = 0;
#pragma unroll
        for (int q = 0; q < 4; ++q) { wo[q] = r; r += ws[q]; }
    }
    __syncthreads();
    const int excl = incl - v + wo[w];

    __shared__ int blockoff;
    if (t == (int)blockIdx.x) blockoff = excl;
    if (blockIdx.x == NB - 1 && t == NB - 1) row_start[n_nodes] = excl + v;
    __syncthreads();

    const int C = (n_nodes + NB - 1) / NB;
    const int i = blockIdx.x * C + t;
    if (t < C && i < n_nodes) {
        int r = local[i] + blockoff;
        row_start[i] = r;
        cursor[i]    = r;
    }
}

// ---------------------------------------------------------------------------
// K4: scatter (edge_id, src_id, dst_id, 0) int4 records into CSR order.
// ---------------------------------------------------------------------------
__global__ void __launch_bounds__(256) scatter_kernel(
    const int* __restrict__ dst, const int* __restrict__ src,
    int* __restrict__ cursor, int4* __restrict__ csr, int n_edges)
{
    const int half = (n_edges + 1) >> 1;
    const int g = blockIdx.x * blockDim.x + threadIdx.x;
    if (g >= half) return;
    const int e1 = g + half;
    const bool h1 = e1 < n_edges;
    const int d0 = dst[g];
    const int s0 = src[g];
    const int d1 = h1 ? dst[e1] : 0;
    const int s1 = h1 ? src[e1] : 0;
    const int p0 = atomicAdd(&cursor[d0], 1);
    const int p1 = h1 ? atomicAdd(&cursor[d1], 1) : 0;
    csr[p0] = make_int4(g, s0, d0, 0);
    if (h1) csr[p1] = make_int4(e1, s1, d1, 0);
}

// ---------------------------------------------------------------------------
// K5: MFMA edge-message + segment aggregation (unchanged from R11).
// ---------------------------------------------------------------------------
__global__ void __launch_bounds__(128) agg_mfma_kernel(
    const float* __restrict__ edge,
    const float* __restrict__ W_e, const float* __restrict__ b_e,
    const float* __restrict__ Ps, const float* __restrict__ Pd,
    const int* __restrict__ row_start, const int4* __restrict__ csr,
    float* __restrict__ msum, int n_edges)
{
    __shared__ unsigned lds_m[2][32][68];   // 17.4 KB: bf16-paired raw scores

    const int t    = threadIdx.x;
    const int lane = t & 63;
    const int wid  = __builtin_amdgcn_readfirstlane((int)(t >> 6));
    const int wbeg = blockIdx.x * TP + wid * 64;
    const int wcnt = min(n_edges - wbeg, 64);
    if (wcnt <= 0) return;

    const int l15 = lane & 15;
    const int k0  = (lane >> 4) << 3;

    bfu bfr[4];
#pragma unroll
    for (int Nt = 0; Nt < 4; ++Nt) {
        const int col = (Nt << 4) | l15;
        float wv[8];
#pragma unroll
        for (int e = 0; e < 8; ++e)
            wv[e] = W_e[(64 + k0 + e) * DO + col];
#pragma unroll
        for (int v2 = 0; v2 < 4; ++v2)
            bfr[Nt].u[v2] = pack_bf16(wv[2 * v2], wv[2 * v2 + 1]);
    }
    const float bj = b_e[lane];

    const int4 my4 = csr[min(wbeg + lane, n_edges - 1)];

#pragma unroll
    for (int Mt = 0; Mt < 4; ++Mt) {
        const int eA = __shfl(my4.x, (Mt << 4) | l15, 64);
        const float* __restrict__ ep = edge + (size_t)(unsigned)eA * DE + k0;
        const float4 f0 = *(const float4*)(ep);
        const float4 f1 = *(const float4*)(ep + 4);
        bfu afr;
        afr.u[0] = pack_bf16(f0.x, f0.y);
        afr.u[1] = pack_bf16(f0.z, f0.w);
        afr.u[2] = pack_bf16(f1.x, f1.y);
        afr.u[3] = pack_bf16(f1.z, f1.w);
        const int rp0 = (Mt << 3) + ((lane >> 4) << 1);
#pragma unroll
        for (int Nt = 0; Nt < 4; ++Nt) {
            f32x4 dz = {0.f, 0.f, 0.f, 0.f};
            f32x4 d = __builtin_amdgcn_mfma_f32_16x16x32_bf16(afr.v, bfr[Nt].v, dz, 0, 0, 0);
            const int col = (Nt << 4) | l15;
            lds_m[wid][rp0][col]     = pack_bf16(d[0], d[1]);
            lds_m[wid][rp0 + 1][col] = pack_bf16(d[2], d[3]);
        }
    }

    float acc = 0.f, bpd = 0.f;
    int cur_d = -1;

    if (wcnt == 64) {
        float pn[CH];
#pragma unroll
        for (int q = 0; q < CH; ++q) {
            const int s = __builtin_amdgcn_readlane(my4.y, q);
            pn[q] = Ps[(unsigned)s * DO + lane];
        }
#pragma unroll
        for (int c = 0; c < 64; c += CH) {
            float pc[CH];
#pragma unroll
            for (int q = 0; q < CH; ++q) pc[q] = pn[q];
            if (c + CH < 64) {
#pragma unroll
                for (int q = 0; q < CH; ++q) {
                    const int s = __builtin_amdgcn_readlane(my4.y, c + CH + q);
                    pn[q] = Ps[(unsigned)s * DO + lane];
                }
            }
            unsigned um[4];
#pragma unroll
            for (int h = 0; h < 4; ++h)
                um[h] = lds_m[wid][(c >> 1) + h][lane];
#pragma unroll
            for (int q = 0; q < CH; ++q) {
                const int p = c + q;
                const int d = __builtin_amdgcn_readlane(my4.z, p);
                if (d != cur_d) {
                    if (cur_d >= 0) {
                        if (row_start[cur_d] >= wbeg)
                            msum[(size_t)cur_d * DO + lane] = acc;
                        else
                            unsafeAtomicAdd(&msum[(size_t)cur_d * DO + lane], acc);
                    }
                    acc = 0.f;
                    cur_d = d;
                    bpd = bj + Pd[(unsigned)d * DO + lane];
                }
                const unsigned u = um[q >> 1];
                const float mv = (q & 1) ? __uint_as_float(u & 0xffff0000u)
                                         : __uint_as_float(u << 16);
                acc += fmaxf(mv + bpd + pc[q], 0.f);
            }
        }
    } else {
        for (int p = 0; p < wcnt; ++p) {
            const int d = __builtin_amdgcn_readlane(my4.z, p);
            const int s = __builtin_amdgcn_readlane(my4.y, p);
            const float ps = Ps[(unsigned)s * DO + lane];
            if (d != cur_d) {
                if (cur_d >= 0) {
                    if (row_start[cur_d] >= wbeg)
                        msum[(size_t)cur_d * DO + lane] = acc;
                    else
                        unsafeAtomicAdd(&msum[(size_t)cur_d * DO + lane], acc);
                }
                acc = 0.f;
                cur_d = d;
                bpd = bj + Pd[(unsigned)d * DO + lane];
            }
            const unsigned u = lds_m[wid][p >> 1][lane];
            const float mv = (p & 1) ? __uint_as_float(u & 0xffff0000u)
                                     : __uint_as_float(u << 16);
            acc += fmaxf(mv + bpd + ps, 0.f);
        }
    }

    {
        const int sb = row_start[cur_d];
        const int se = row_start[cur_d + 1];
        if (sb >= wbeg && se <= wbeg + wcnt)
            msum[(size_t)cur_d * DO + lane] = acc;
        else
            unsafeAtomicAdd(&msum[(size_t)cur_d * DO + lane], acc);
    }
}

// ---------------------------------------------------------------------------
// K6: MFMA node update: out = relu((msum@Wt)/deg + node@Wb + b_v).
// Same tile scheme as K1; deg folded in post-MFMA (per-row scalar).
// ---------------------------------------------------------------------------
__global__ void __launch_bounds__(256) node_out_kernel(
    const float* __restrict__ node, const float* __restrict__ msum,
    const int* __restrict__ row_start,
    const float* __restrict__ W_v, const float* __restrict__ b_v,
    float* __restrict__ out, int n_nodes)
{
    const int t    = threadIdx.x;
    const int lane = t & 63;
    const int w    = __builtin_amdgcn_readfirstlane((int)(t >> 6));
    const int l15  = lane & 15;
    const int k0   = (lane >> 4) << 3;

    bfu bT[4][2], bB[4][2];
#pragma unroll
    for (int Nt = 0; Nt < 4; ++Nt) {
        const int col = (Nt << 4) | l15;
#pragma unroll
        for (int ks = 0; ks < 2; ++ks) {
            float wt[8], wb[8];
#pragma unroll
            for (int e = 0; e < 8; ++e) {
                wt[e] = W_v[(ks * 32 + k0 + e) * DO + col];
                wb[e] = W_v[(64 + ks * 32 + k0 + e) * DO + col];
            }
#pragma unroll
            for (int q = 0; q < 4; ++q) {
                bT[Nt][ks].u[q] = pack_bf16(wt[2 * q], wt[2 * q + 1]);
                bB[Nt][ks].u[q] = pack_bf16(wb[2 * q], wb[2 * q + 1]);
            }
        }
    }

    const int row0 = blockIdx.x * 64 + w * 16;
    if (row0 >= n_nodes) return;

    bfu aM[2], aN[2];
#pragma unroll
    for (int ks = 0; ks < 2; ++ks) {
        const int r = min(row0 + l15, n_nodes - 1);
        const float* __restrict__ pm = msum + (size_t)r * DO + ks * 32 + k0;
        const float* __restrict__ pn = node + (size_t)r * DN + ks * 32 + k0;
        const float4 m0 = *(const float4*)pm;
        const float4 m1 = *(const float4*)(pm + 4);
        const float4 n0 = *(const float4*)pn;
        const float4 n1 = *(const float4*)(pn + 4);
        aM[ks].u[0] = pack_bf16(m0.x, m0.y);
        aM[ks].u[1] = pack_bf16(m0.z, m0.w);
        aM[ks].u[2] = pack_bf16(m1.x, m1.y);
        aM[ks].u[3] = pack_bf16(m1.z, m1.w);
        aN[ks].u[0] = pack_bf16(n0.x, n0.y);
        aN[ks].u[1] = pack_bf16(n0.z, n0.w);
        aN[ks].u[2] = pack_bf16(n1.x, n1.y);
        aN[ks].u[3] = pack_bf16(n1.z, n1.w);
    }

    f32x4 accT[4], accB[4];
#pragma unroll
    for (int Nt = 0; Nt < 4; ++Nt) {
        const f32x4 z = {0.f, 0.f, 0.f, 0.f};
        f32x4 aT = __builtin_amdgcn_mfma_f32_16x16x32_bf16(aM[0].v, bT[Nt][0].v, z, 0, 0, 0);
        aT = __builtin_amdgcn_mfma_f32_16x16x32_bf16(aM[1].v, bT[Nt][1].v, aT, 0, 0, 0);
        f32x4 aB = __builtin_amdgcn_mfma_f32_16x16x32_bf16(aN[0].v, bB[Nt][0].v, z, 0, 0, 0);
        aB = __builtin_amdgcn_mfma_f32_16x16x32_bf16(aN[1].v, bB[Nt][1].v, aB, 0, 0, 0);
        accT[Nt] = aT;
        accB[Nt] = aB;
    }

    const int rb = row0 + ((lane >> 4) << 2);
#pragma unroll
    for (int r = 0; r < 4; ++r) {
        const int row = rb + r;
        if (row < n_nodes) {
            const float dg = (float)(row_start[row + 1] - row_start[row]);
            const float inv = (dg > 0.f) ? 1.f / dg : 0.f;
#pragma unroll
            for (int Nt = 0; Nt < 4; ++Nt) {
                const int col = (Nt << 4) | l15;
                const float val = accT[Nt][r] * inv + accB[Nt][r] + b_v[col];
                out[(size_t)row * DO + col] = fmaxf(val, 0.f);
            }
        }
    }
}

extern "C" void kernel_launch(void* const* d_in, const int* in_sizes, int n_in,
                              void* d_out, int out_size, void* d_ws, size_t ws_size,
                              hipStream_t stream)
{
    const float* node = (const float*)d_in[0];
    const float* edge = (const float*)d_in[1];
    const int*   src  = (const int*)d_in[2];
    const int*   dst  = (const int*)d_in[3];
    const float* W_e  = (const float*)d_in[4];
    const float* b_e  = (const float*)d_in[5];
    const float* W_v  = (const float*)d_in[6];
    const float* b_v  = (const float*)d_in[7];
    float* out = (float*)d_out;

    const int n_nodes = in_sizes[0] / DN;
    const int n_edges = in_sizes[2];
    const int ntiles  = (n_nodes + 63) / 64;

    // Workspace: Ps | Pd | msum (floats) | row_start | cnt | cursor | local | bsum | csr(int4)
    float* Ps   = (float*)d_ws;
    float* Pd   = Ps   + (size_t)n_nodes * DO;
    float* msum = Pd   + (size_t)n_nodes * DO;
    int* row_start = (int*)(msum + (size_t)n_nodes * DO);
    int* cnt       = row_start + (n_nodes + 1);
    int* cursor    = cnt + n_nodes;
    int* local     = cursor + n_nodes;
    int* bsum      = local + n_nodes;
    int4* csr      = (int4*)(((size_t)(bsum + NB) + 15) & ~(size_t)15);

    hipMemsetAsync(msum, 0, (size_t)n_nodes * DO * sizeof(float), stream);
    hipMemsetAsync(cnt, 0, (size_t)n_nodes * sizeof(int), stream);

    pre_hist_kernel<<<ntiles, 256, 0, stream>>>(node, W_e, dst, Ps, Pd, cnt,
                                                n_nodes, n_edges);
    scan_partial<<<NB, 256, 0, stream>>>(cnt, local, bsum, n_nodes);
    scan_final<<<NB, 256, 0, stream>>>(local, bsum, row_start, cursor, n_nodes);
    scatter_kernel<<<((n_edges + 1) / 2 + 255) / 256, 256, 0, stream>>>(dst, src, cursor, csr, n_edges);
    agg_mfma_kernel<<<(n_edges + TP - 1) / TP, 128, 0, stream>>>(edge, W_e, b_e, Ps, Pd,
                                                                 row_start, csr, msum, n_edges);
    node_out_kernel<<<ntiles, 256, 0, stream>>>(node, msum, row_start, W_v, b_v,
                                                out, n_nodes);
}

// Round 13
// 163.897 us; speedup vs baseline: 2.4337x; 1.0996x over previous
//
#include <hip/hip_runtime.h>

#define DN 64
#define DE 32
#define DO 64
#define NB 256   // scan phase-1 blocks (requires n_nodes <= NB*256)
#define TP 128   // CSR positions per agg block (2 waves x 64)
#define CH 8     // Ps prefetch chunk

typedef __attribute__((ext_vector_type(8))) short bf16x8;
typedef __attribute__((ext_vector_type(4))) float f32x4;

__device__ inline unsigned pack_bf16(float a, float b) {
    unsigned ua = __float_as_uint(a), ub = __float_as_uint(b);
    ua = (ua + 0x7fffu + ((ua >> 16) & 1u)) >> 16;     // RNE bf16
    ub = (ub + 0x7fffu + ((ub >> 16) & 1u)) >> 16;
    return ua | (ub << 16);
}
__device__ inline unsigned short bf16_1(float a) {
    unsigned u = __float_as_uint(a);
    return (unsigned short)((u + 0x7fffu + ((u >> 16) & 1u)) >> 16);
}
__device__ inline float bf16f(unsigned short v) {
    return __uint_as_float((unsigned)v << 16);
}

union bfu { unsigned u[4]; bf16x8 v; };

// ---------------------------------------------------------------------------
// K1: MFMA per-node projections (-> PACKED BF16 tables) + degree histogram.
// ---------------------------------------------------------------------------
__global__ void __launch_bounds__(256) pre_hist_kernel(
    const float* __restrict__ node, const float* __restrict__ W_e,
    const int* __restrict__ dst,
    unsigned short* __restrict__ PsB, unsigned short* __restrict__ PdB,
    int* __restrict__ cnt, int n_nodes, int n_edges)
{
    const int t    = threadIdx.x;
    const int lane = t & 63;
    const int w    = __builtin_amdgcn_readfirstlane((int)(t >> 6));
    const int l15  = lane & 15;
    const int k0   = (lane >> 4) << 3;

    bfu bS[4][2], bD[4][2];
#pragma unroll
    for (int Nt = 0; Nt < 4; ++Nt) {
        const int col = (Nt << 4) | l15;
#pragma unroll
        for (int ks = 0; ks < 2; ++ks) {
            float ws[8], wd[8];
#pragma unroll
            for (int e = 0; e < 8; ++e) {
                ws[e] = W_e[(ks * 32 + k0 + e) * DO + col];
                wd[e] = W_e[(96 + ks * 32 + k0 + e) * DO + col];
            }
#pragma unroll
            for (int q = 0; q < 4; ++q) {
                bS[Nt][ks].u[q] = pack_bf16(ws[2 * q], ws[2 * q + 1]);
                bD[Nt][ks].u[q] = pack_bf16(wd[2 * q], wd[2 * q + 1]);
            }
        }
    }

    const int row0 = blockIdx.x * 64 + w * 16;
    if (row0 < n_nodes) {
        bfu aF[2];
#pragma unroll
        for (int ks = 0; ks < 2; ++ks) {
            const int r = min(row0 + l15, n_nodes - 1);
            const float* __restrict__ p = node + (size_t)r * DN + ks * 32 + k0;
            const float4 f0 = *(const float4*)p;
            const float4 f1 = *(const float4*)(p + 4);
            aF[ks].u[0] = pack_bf16(f0.x, f0.y);
            aF[ks].u[1] = pack_bf16(f0.z, f0.w);
            aF[ks].u[2] = pack_bf16(f1.x, f1.y);
            aF[ks].u[3] = pack_bf16(f1.z, f1.w);
        }
        const int rb = row0 + ((lane >> 4) << 2);
#pragma unroll
        for (int Nt = 0; Nt < 4; ++Nt) {
            const f32x4 z = {0.f, 0.f, 0.f, 0.f};
            f32x4 aS = __builtin_amdgcn_mfma_f32_16x16x32_bf16(aF[0].v, bS[Nt][0].v, z, 0, 0, 0);
            aS = __builtin_amdgcn_mfma_f32_16x16x32_bf16(aF[1].v, bS[Nt][1].v, aS, 0, 0, 0);
            f32x4 aD = __builtin_amdgcn_mfma_f32_16x16x32_bf16(aF[0].v, bD[Nt][0].v, z, 0, 0, 0);
            aD = __builtin_amdgcn_mfma_f32_16x16x32_bf16(aF[1].v, bD[Nt][1].v, aD, 0, 0, 0);
            const int col = (Nt << 4) | l15;
#pragma unroll
            for (int r = 0; r < 4; ++r) {
                if (rb + r < n_nodes) {
                    PsB[(size_t)(rb + r) * DO + col] = bf16_1(aS[r]);
                    PdB[(size_t)(rb + r) * DO + col] = bf16_1(aD[r]);
                }
            }
        }
    }

    const int gt = blockIdx.x * blockDim.x + t;
    const int nt = gridDim.x * blockDim.x;
    for (int e = gt; e < n_edges; e += nt)
        atomicAdd(&cnt[dst[e]], 1);
}

// ---------------------------------------------------------------------------
// K3a: per-block local exclusive scan + block sums
// ---------------------------------------------------------------------------
__global__ void __launch_bounds__(256) scan_partial(
    const int* __restrict__ cnt, int* __restrict__ local,
    int* __restrict__ bsum, int n_nodes)
{
    const int C = (n_nodes + NB - 1) / NB;
    const int t = threadIdx.x, lane = t & 63, w = t >> 6;
    const int i = blockIdx.x * C + t;

    int v = (t < C && i < n_nodes) ? cnt[i] : 0;
    int incl = v;
#pragma unroll
    for (int off = 1; off < 64; off <<= 1) {
        int u = __shfl_up(incl, off, 64);
        if (lane >= off) incl += u;
    }
    __shared__ int ws[4], wo[4];
    if (lane == 63) ws[w] = incl;
    __syncthreads();
    if (t == 0) {
        int r = 0;
#pragma unroll
        for (int q = 0; q < 4; ++q) { wo[q] = r; r += ws[q]; }
        bsum[blockIdx.x] = r;
    }
    __syncthreads();
    if (t < C && i < n_nodes) local[i] = incl - v + wo[w];
}

// ---------------------------------------------------------------------------
// K3b: merged bsum-scan + add
// ---------------------------------------------------------------------------
__global__ void __launch_bounds__(256) scan_final(
    const int* __restrict__ local, const int* __restrict__ bsum,
    int* __restrict__ row_start, int* __restrict__ cursor, int n_nodes)
{
    const int t = threadIdx.x, lane = t & 63, w = t >> 6;
    int v = bsum[t];
    int incl = v;
#pragma unroll
    for (int off = 1; off < 64; off <<= 1) {
        int u = __shfl_up(incl, off, 64);
        if (lane >= off) incl += u;
    }
    __shared__ int ws[4], wo[4];
    if (lane == 63) ws[w] = incl;
    __syncthreads();
    if (t == 0) {
        int r = 0;
#pragma unroll
        for (int q = 0; q < 4; ++q) { wo[q] = r; r += ws[q]; }
    }
    __syncthreads();
    const int excl = incl - v + wo[w];

    __shared__ int blockoff;
    if (t == (int)blockIdx.x) blockoff = excl;
    if (blockIdx.x == NB - 1 && t == NB - 1) row_start[n_nodes] = excl + v;
    __syncthreads();

    const int C = (n_nodes + NB - 1) / NB;
    const int i = blockIdx.x * C + t;
    if (t < C && i < n_nodes) {
        int r = local[i] + blockoff;
        row_start[i] = r;
        cursor[i]    = r;
    }
}

// ---------------------------------------------------------------------------
// K4: scatter int2 (e, s | d<<16) records into CSR order.
// ---------------------------------------------------------------------------
__global__ void __launch_bounds__(256) scatter_kernel(
    const int* __restrict__ dst, const int* __restrict__ src,
    int* __restrict__ cursor, int2* __restrict__ csr, int n_edges)
{
    const int half = (n_edges + 1) >> 1;
    const int g = blockIdx.x * blockDim.x + threadIdx.x;
    if (g >= half) return;
    const int e1 = g + half;
    const bool h1 = e1 < n_edges;
    const int d0 = dst[g];
    const int s0 = src[g];
    const int d1 = h1 ? dst[e1] : 0;
    const int s1 = h1 ? src[e1] : 0;
    const int p0 = atomicAdd(&cursor[d0], 1);
    const int p1 = h1 ? atomicAdd(&cursor[d1], 1) : 0;
    csr[p0] = make_int2(g, s0 | (d0 << 16));
    if (h1) csr[p1] = make_int2(e1, s1 | (d1 << 16));
}

// ---------------------------------------------------------------------------
// K5: MFMA edge-message + segment aggregation.
// Changes vs R12: csr int2 (s|d<<16 unpack, UNSIGNED shift for d);
// Ps/Pd read as bf16 (2B/lane gathers, table ~L2-resident);
// 3-buffer 2-chunk-deep Ps prefetch (~2 iterations = 300-400 cyc cover).
// ---------------------------------------------------------------------------
__global__ void __launch_bounds__(128) agg_mfma_kernel(
    const float* __restrict__ edge,
    const float* __restrict__ W_e, const float* __restrict__ b_e,
    const unsigned short* __restrict__ PsB, const unsigned short* __restrict__ PdB,
    const int* __restrict__ row_start, const int2* __restrict__ csr,
    float* __restrict__ msum, int n_edges)
{
    __shared__ unsigned lds_m[2][32][68];   // 17.4 KB: bf16-paired raw scores

    const int t    = threadIdx.x;
    const int lane = t & 63;
    const int wid  = __builtin_amdgcn_readfirstlane((int)(t >> 6));
    const int wbeg = blockIdx.x * TP + wid * 64;
    const int wcnt = min(n_edges - wbeg, 64);
    if (wcnt <= 0) return;

    const int l15 = lane & 15;
    const int k0  = (lane >> 4) << 3;

    bfu bfr[4];
#pragma unroll
    for (int Nt = 0; Nt < 4; ++Nt) {
        const int col = (Nt << 4) | l15;
        float wv[8];
#pragma unroll
        for (int e = 0; e < 8; ++e)
            wv[e] = W_e[(64 + k0 + e) * DO + col];
#pragma unroll
        for (int v2 = 0; v2 < 4; ++v2)
            bfr[Nt].u[v2] = pack_bf16(wv[2 * v2], wv[2 * v2 + 1]);
    }
    const float bj = b_e[lane];

    const int2 my2 = csr[min(wbeg + lane, n_edges - 1)];

#pragma unroll
    for (int Mt = 0; Mt < 4; ++Mt) {
        const int eA = __shfl(my2.x, (Mt << 4) | l15, 64);
        const float* __restrict__ ep = edge + (size_t)(unsigned)eA * DE + k0;
        const float4 f0 = *(const float4*)(ep);
        const float4 f1 = *(const float4*)(ep + 4);
        bfu afr;
        afr.u[0] = pack_bf16(f0.x, f0.y);
        afr.u[1] = pack_bf16(f0.z, f0.w);
        afr.u[2] = pack_bf16(f1.x, f1.y);
        afr.u[3] = pack_bf16(f1.z, f1.w);
        const int rp0 = (Mt << 3) + ((lane >> 4) << 1);
#pragma unroll
        for (int Nt = 0; Nt < 4; ++Nt) {
            f32x4 dz = {0.f, 0.f, 0.f, 0.f};
            f32x4 d = __builtin_amdgcn_mfma_f32_16x16x32_bf16(afr.v, bfr[Nt].v, dz, 0, 0, 0);
            const int col = (Nt << 4) | l15;
            lds_m[wid][rp0][col]     = pack_bf16(d[0], d[1]);
            lds_m[wid][rp0 + 1][col] = pack_bf16(d[2], d[3]);
        }
    }

    float acc = 0.f, bpd = 0.f;
    int cur_d = -1;

#define FLUSH()                                                         \
    {                                                                   \
        if (row_start[cur_d] >= wbeg)                                   \
            msum[(size_t)cur_d * DO + lane] = acc;                      \
        else                                                            \
            unsafeAtomicAdd(&msum[(size_t)cur_d * DO + lane], acc);     \
    }

#define ISSUE(CHK, BUF)                                                 \
    _Pragma("unroll")                                                   \
    for (int q = 0; q < CH; ++q) {                                      \
        const int y = __builtin_amdgcn_readlane(my2.y, (CHK) * CH + q); \
        BUF[q] = PsB[(size_t)(unsigned)(y & 0xffff) * DO + lane];       \
    }

#define CONSUME(CHK, BUF)                                               \
    {                                                                   \
        unsigned um[4];                                                 \
        _Pragma("unroll")                                               \
        for (int h = 0; h < 4; ++h)                                     \
            um[h] = lds_m[wid][(CHK) * 4 + h][lane];                    \
        _Pragma("unroll")                                               \
        for (int q = 0; q < CH; ++q) {                                  \
            const int y = __builtin_amdgcn_readlane(my2.y, (CHK) * CH + q); \
            const int d = (int)(((unsigned)y) >> 16);                   \
            if (d != cur_d) {                                           \
                if (cur_d >= 0) FLUSH();                                \
                acc = 0.f;                                              \
                cur_d = d;                                              \
                bpd = bj + bf16f(PdB[(size_t)(unsigned)d * DO + lane]); \
            }                                                           \
            const unsigned u = um[q >> 1];                              \
            const float mv = (q & 1) ? __uint_as_float(u & 0xffff0000u) \
                                     : __uint_as_float(u << 16);        \
            acc += fmaxf(mv + bpd + __uint_as_float((unsigned)BUF[q] << 16), 0.f); \
        }                                                               \
    }

    if (wcnt == 64) {
        unsigned short pnA[CH], pnB[CH], pnC[CH];
        ISSUE(0, pnA) ISSUE(1, pnB)
        ISSUE(2, pnC) CONSUME(0, pnA)
        ISSUE(3, pnA) CONSUME(1, pnB)
        ISSUE(4, pnB) CONSUME(2, pnC)
        ISSUE(5, pnC) CONSUME(3, pnA)
        ISSUE(6, pnA) CONSUME(4, pnB)
        ISSUE(7, pnB) CONSUME(5, pnC)
        CONSUME(6, pnA)
        CONSUME(7, pnB)
    } else {
        for (int p = 0; p < wcnt; ++p) {
            const int y = __builtin_amdgcn_readlane(my2.y, p);
            const int s = y & 0xffff;
            const int d = (int)(((unsigned)y) >> 16);
            const float ps = bf16f(PsB[(size_t)(unsigned)s * DO + lane]);
            if (d != cur_d) {
                if (cur_d >= 0) FLUSH();
                acc = 0.f;
                cur_d = d;
                bpd = bj + bf16f(PdB[(size_t)(unsigned)d * DO + lane]);
            }
            const unsigned u = lds_m[wid][p >> 1][lane];
            const float mv = (p & 1) ? __uint_as_float(u & 0xffff0000u)
                                     : __uint_as_float(u << 16);
            acc += fmaxf(mv + bpd + ps, 0.f);
        }
    }

    {   // final flush
        const int sb = row_start[cur_d];
        const int se = row_start[cur_d + 1];
        if (sb >= wbeg && se <= wbeg + wcnt)
            msum[(size_t)cur_d * DO + lane] = acc;
        else
            unsafeAtomicAdd(&msum[(size_t)cur_d * DO + lane], acc);
    }
#undef FLUSH
#undef ISSUE
#undef CONSUME
}

// ---------------------------------------------------------------------------
// K6: MFMA node update: out = relu((msum@Wt)/deg + node@Wb + b_v).
// ---------------------------------------------------------------------------
__global__ void __launch_bounds__(256) node_out_kernel(
    const float* __restrict__ node, const float* __restrict__ msum,
    const int* __restrict__ row_start,
    const float* __restrict__ W_v, const float* __restrict__ b_v,
    float* __restrict__ out, int n_nodes)
{
    const int t    = threadIdx.x;
    const int lane = t & 63;
    const int w    = __builtin_amdgcn_readfirstlane((int)(t >> 6));
    const int l15  = lane & 15;
    const int k0   = (lane >> 4) << 3;

    bfu bT[4][2], bB[4][2];
#pragma unroll
    for (int Nt = 0; Nt < 4; ++Nt) {
        const int col = (Nt << 4) | l15;
#pragma unroll
        for (int ks = 0; ks < 2; ++ks) {
            float wt[8], wb[8];
#pragma unroll
            for (int e = 0; e < 8; ++e) {
                wt[e] = W_v[(ks * 32 + k0 + e) * DO + col];
                wb[e] = W_v[(64 + ks * 32 + k0 + e) * DO + col];
            }
#pragma unroll
            for (int q = 0; q < 4; ++q) {
                bT[Nt][ks].u[q] = pack_bf16(wt[2 * q], wt[2 * q + 1]);
                bB[Nt][ks].u[q] = pack_bf16(wb[2 * q], wb[2 * q + 1]);
            }
        }
    }

    const int row0 = blockIdx.x * 64 + w * 16;
    if (row0 >= n_nodes) return;

    bfu aM[2], aN[2];
#pragma unroll
    for (int ks = 0; ks < 2; ++ks) {
        const int r = min(row0 + l15, n_nodes - 1);
        const float* __restrict__ pm = msum + (size_t)r * DO + ks * 32 + k0;
        const float* __restrict__ pn = node + (size_t)r * DN + ks * 32 + k0;
        const float4 m0 = *(const float4*)pm;
        const float4 m1 = *(const float4*)(pm + 4);
        const float4 n0 = *(const float4*)pn;
        const float4 n1 = *(const float4*)(pn + 4);
        aM[ks].u[0] = pack_bf16(m0.x, m0.y);
        aM[ks].u[1] = pack_bf16(m0.z, m0.w);
        aM[ks].u[2] = pack_bf16(m1.x, m1.y);
        aM[ks].u[3] = pack_bf16(m1.z, m1.w);
        aN[ks].u[0] = pack_bf16(n0.x, n0.y);
        aN[ks].u[1] = pack_bf16(n0.z, n0.w);
        aN[ks].u[2] = pack_bf16(n1.x, n1.y);
        aN[ks].u[3] = pack_bf16(n1.z, n1.w);
    }

    f32x4 accT[4], accB[4];
#pragma unroll
    for (int Nt = 0; Nt < 4; ++Nt) {
        const f32x4 z = {0.f, 0.f, 0.f, 0.f};
        f32x4 aT = __builtin_amdgcn_mfma_f32_16x16x32_bf16(aM[0].v, bT[Nt][0].v, z, 0, 0, 0);
        aT = __builtin_amdgcn_mfma_f32_16x16x32_bf16(aM[1].v, bT[Nt][1].v, aT, 0, 0, 0);
        f32x4 aB = __builtin_amdgcn_mfma_f32_16x16x32_bf16(aN[0].v, bB[Nt][0].v, z, 0, 0, 0);
        aB = __builtin_amdgcn_mfma_f32_16x16x32_bf16(aN[1].v, bB[Nt][1].v, aB, 0, 0, 0);
        accT[Nt] = aT;
        accB[Nt] = aB;
    }

    const int rb = row0 + ((lane >> 4) << 2);
#pragma unroll
    for (int r = 0; r < 4; ++r) {
        const int row = rb + r;
        if (row < n_nodes) {
            const float dg = (float)(row_start[row + 1] - row_start[row]);
            const float inv = (dg > 0.f) ? 1.f / dg : 0.f;
#pragma unroll
            for (int Nt = 0; Nt < 4; ++Nt) {
                const int col = (Nt << 4) | l15;
                const float val = accT[Nt][r] * inv + accB[Nt][r] + b_v[col];
                out[(size_t)row * DO + col] = fmaxf(val, 0.f);
            }
        }
    }
}

extern "C" void kernel_launch(void* const* d_in, const int* in_sizes, int n_in,
                              void* d_out, int out_size, void* d_ws, size_t ws_size,
                              hipStream_t stream)
{
    const float* node = (const float*)d_in[0];
    const float* edge = (const float*)d_in[1];
    const int*   src  = (const int*)d_in[2];
    const int*   dst  = (const int*)d_in[3];
    const float* W_e  = (const float*)d_in[4];
    const float* b_e  = (const float*)d_in[5];
    const float* W_v  = (const float*)d_in[6];
    const float* b_v  = (const float*)d_in[7];
    float* out = (float*)d_out;

    const int n_nodes = in_sizes[0] / DN;
    const int n_edges = in_sizes[2];
    const int ntiles  = (n_nodes + 63) / 64;

    // Workspace: PsB | PdB (bf16) | msum | cnt (contiguous: one memset) |
    //            row_start | cursor | local | bsum | csr(int2)
    unsigned short* PsB = (unsigned short*)d_ws;
    unsigned short* PdB = PsB + (size_t)n_nodes * DO;
    float* msum = (float*)(PdB + (size_t)n_nodes * DO);
    int* cnt       = (int*)(msum + (size_t)n_nodes * DO);
    int* row_start = cnt + n_nodes;
    int* cursor    = row_start + (n_nodes + 1);
    int* local     = cursor + n_nodes;
    int* bsum      = local + n_nodes;
    int2* csr      = (int2*)(((size_t)(bsum + NB) + 15) & ~(size_t)15);

    // one memset covers msum (n*DO floats) + cnt (n ints), contiguous
    hipMemsetAsync(msum, 0, ((size_t)n_nodes * DO + n_nodes) * sizeof(float), stream);

    pre_hist_kernel<<<ntiles, 256, 0, stream>>>(node, W_e, dst, PsB, PdB, cnt,
                                                n_nodes, n_edges);
    scan_partial<<<NB, 256, 0, stream>>>(cnt, local, bsum, n_nodes);
    scan_final<<<NB, 256, 0, stream>>>(local, bsum, row_start, cursor, n_nodes);
    scatter_kernel<<<((n_edges + 1) / 2 + 255) / 256, 256, 0, stream>>>(dst, src, cursor, csr, n_edges);
    agg_mfma_kernel<<<(n_edges + TP - 1) / TP, 128, 0, stream>>>(edge, W_e, b_e, PsB, PdB,
                                                                 row_start, csr, msum, n_edges);
    node_out_kernel<<<ntiles, 256, 0, stream>>>(node, msum, row_start, W_v, b_v,
                                                out, n_nodes);
}